// Round 10
// baseline (688.216 us; speedup 1.0000x reference)
//
#include <hip/hip_runtime.h>

// TransformerBlock on MI355X (gfx950). External dtype: FP32. Internals bf16.
//   transpose_k: W fp32 [R][C] -> bf16 [C][R]  (64x64 tiles, u32 stores)
//   ln_dual:     nx = LN(x,attn_ln), f = LN(x,ffn_ln)
//   gemm<0,0>:   qkv = nx @ Wqkv + b          (128^2, BK=64, swizzled LDS, 2D grid)
//   qk_rope:     RMSNorm + RoPE(first 32 dims) on q,k   (u32-vectorized)
//   v_transpose: V part of qkv -> vt [b][h][dim][key]
//   attn_mfma:   sliding-window(256) causal flash attention, MFMA, clamped prefetch
//   gemm<2,2>:   tmid = gelu_exact(f @ W1 + b1)   (16x8 XCD supertile)
//   gemm<1,1>:   h = x + y @ Wo + b           (fp32, in d_out; 8x8 XCD supertile)
//   gemm<1,1>:   out = h + tmid @ W2 + b2     (8x8 XCD supertile)
//
// R15 -> R16:
//  (1) attn: spill-proof K/V prefetch.  R11's version spilled because the
//      prefetch regs were conditionally defined/consumed (scratch, 471MB).
//      Now: ONE kreg/vreg set, unconditional clamped tn=min(t+1,g), loads
//      issued AFTER the staging barrier -> fly under QK/softmax/PV compute;
//      next iteration's barrier drain lands post-compute (no stall).
//  (2) FFN1 gets the square-region XCD remap validated on WO/W2, sized for
//      its 32x32 grid (8 XCDs as 2x4 bands of 16x8 tiles).

typedef unsigned short u16;
typedef unsigned int   u32;
typedef __bf16 bf16x8 __attribute__((ext_vector_type(8)));
typedef float  f32x4  __attribute__((ext_vector_type(4)));
typedef __attribute__((address_space(3))) u32 as3_u32;
typedef __attribute__((address_space(1))) u32 as1_u32;

#define B_    2
#define S_    2048
#define D_    2048
#define H_    16
#define HD_   128
#define FF_   4096
#define WIN_  256
#define EPS_  1e-5f
#define SCALE_ 0.08838834764831845f  // 1/sqrt(128)

__device__ __forceinline__ float b2f(u16 u) {
    return __uint_as_float(((u32)u) << 16);
}
__device__ __forceinline__ u16 f2b(float f) {
    u32 u = __float_as_uint(f);
    u32 r = (u + 0x7fffu + ((u >> 16) & 1u)) >> 16;  // RNE
    return (u16)r;
}
__device__ __forceinline__ float wave_sum(float v) {
#pragma unroll
    for (int o = 32; o > 0; o >>= 1) v += __shfl_xor(v, o);
    return v;
}
// async 16B/lane global->LDS; lds base must be wave-uniform, lane i lands at
// base + i*16 (m97 pattern).
__device__ __forceinline__ void gld_lds16(const u16* g, u16* l) {
    __builtin_amdgcn_global_load_lds((const as1_u32*)g, (as3_u32*)l, 16, 0, 0);
}

// -------- weight transpose + cast: in fp32 [R][C] -> out bf16 [C][R] -------
// 64x64 tile; write phase packs row-pairs into u32 (contiguous along R).
__global__ __launch_bounds__(256) void transpose_k(const float* __restrict__ in,
                                                   u16* __restrict__ out,
                                                   int R, int C) {
    __shared__ float tile[64][65];
    int t = threadIdx.x;
    int r0 = blockIdx.y * 64, c0 = blockIdx.x * 64;
    int rr = t >> 2;              // 0..63
    int cb = (t & 3) * 16;        // 0,16,32,48
    const float* src = &in[(size_t)(r0 + rr) * C + c0 + cb];
#pragma unroll
    for (int j = 0; j < 16; j += 4) {
        float4 v = *(const float4*)&src[j];
        tile[rr][cb + j]     = v.x; tile[rr][cb + j + 1] = v.y;
        tile[rr][cb + j + 2] = v.z; tile[rr][cb + j + 3] = v.w;
    }
    __syncthreads();
    int wq = t & 31;              // row-pair 0..31 (rows 2wq, 2wq+1)
    int ch = t >> 5;              // 0..7
#pragma unroll
    for (int i = 0; i < 8; ++i) {
        int c = ch * 8 + i;       // 0..63
        u32 lo = (u32)f2b(tile[2 * wq][c]);
        u32 hi = (u32)f2b(tile[2 * wq + 1][c]);
        ((u32*)out)[(((size_t)(c0 + c) * R) >> 1) + (r0 >> 1) + wq] = lo | (hi << 16);
    }
}

// ---------- dual LayerNorm: fp32 x -> bf16 nx, f (one pass) ----------------
__global__ __launch_bounds__(256) void ln_dual(const float* __restrict__ x,
        const float* __restrict__ aw, const float* __restrict__ ab,
        const float* __restrict__ fw, const float* __restrict__ fb,
        u16* __restrict__ nx, u16* __restrict__ f) {
    int row = blockIdx.x;                // 0..B*S-1
    const float* xr = x + (size_t)row * D_;
    int base = threadIdx.x * 8;
    float4 xa = *(const float4*)&xr[base];
    float4 xb = *(const float4*)&xr[base + 4];
    float xv[8] = {xa.x, xa.y, xa.z, xa.w, xb.x, xb.y, xb.z, xb.w};
    float s = 0.f, s2 = 0.f;
#pragma unroll
    for (int i = 0; i < 8; ++i) { s += xv[i]; s2 += xv[i] * xv[i]; }
    s = wave_sum(s); s2 = wave_sum(s2);
    __shared__ float r1[4], r2[4];
    int w = threadIdx.x >> 6;
    if ((threadIdx.x & 63) == 0) { r1[w] = s; r2[w] = s2; }
    __syncthreads();
    float ts  = r1[0] + r1[1] + r1[2] + r1[3];
    float ts2 = r2[0] + r2[1] + r2[2] + r2[3];
    float mean = ts * (1.f / D_);
    float var  = ts2 * (1.f / D_) - mean * mean;
    float inv  = rsqrtf(var + EPS_);
    float4 wa0 = *(const float4*)&aw[base], wa1 = *(const float4*)&aw[base + 4];
    float4 ba0 = *(const float4*)&ab[base], ba1 = *(const float4*)&ab[base + 4];
    float4 wf0 = *(const float4*)&fw[base], wf1 = *(const float4*)&fw[base + 4];
    float4 bf0 = *(const float4*)&fb[base], bf1 = *(const float4*)&fb[base + 4];
    float wav[8] = {wa0.x, wa0.y, wa0.z, wa0.w, wa1.x, wa1.y, wa1.z, wa1.w};
    float bav[8] = {ba0.x, ba0.y, ba0.z, ba0.w, ba1.x, ba1.y, ba1.z, ba1.w};
    float wfv[8] = {wf0.x, wf0.y, wf0.z, wf0.w, wf1.x, wf1.y, wf1.z, wf1.w};
    float bfv[8] = {bf0.x, bf0.y, bf0.z, bf0.w, bf1.x, bf1.y, bf1.z, bf1.w};
    union { uint4 v; u16 s[8]; } o1, o2;
#pragma unroll
    for (int i = 0; i < 8; ++i) {
        float t = (xv[i] - mean) * inv;
        o1.s[i] = f2b(t * wav[i] + bav[i]);
        o2.s[i] = f2b(t * wfv[i] + bfv[i]);
    }
    *(uint4*)&nx[(size_t)row * D_ + base] = o1.v;
    *(uint4*)&f [(size_t)row * D_ + base] = o2.v;
}

// ---------------- MFMA GEMM: 128^2 tile, BK=64, swizzled LDS ---------------
// m97 2-phase structure with BK=64 + XOR LDS swizzle (QKV 99-102us @ ~48%
// MfmaUtil, conflicts 0).
// SWZ=0: plain 2D grid.  SWZ=1: WO/W2 map (grid 512, 8 XCD supertiles of
// 8x8 tiles).  SWZ=2: FFN1 map (grid 1024, 8 XCDs as 2x4 bands of 16x8).
// EPI 0: bf16 out.  EPI 1: fp32 out, += fp32 residual.  EPI 2: bf16, GELU.
template <int EPI, int SWZ>
__global__ __launch_bounds__(256, 2) void gemm_bt(
        const u16* __restrict__ A, const u16* __restrict__ BT,
        const float* __restrict__ bias, const float* __restrict__ res,
        void* __restrict__ Cv, int M, int N, int K) {
    __shared__ __align__(16) u16 As[128][64];
    __shared__ __align__(16) u16 Bs[128][64];
    int m0, n0;
    if (SWZ == 0) {
        m0 = blockIdx.y * 128; n0 = blockIdx.x * 128;
    } else if (SWZ == 1) {
        // grid = 512: XCD xc owns the 8x8-tile supertile (xc>>1, xc&1)
        int bid = blockIdx.x;
        int xc = bid & 7, ii = bid >> 3;
        int by = (xc >> 1) * 8 + (ii >> 3);
        int bx = (xc & 1) * 8 + (ii & 7);
        m0 = by * 128; n0 = bx * 128;
    } else {
        // grid = 1024 (32x32 tiles): XCD xc owns a 16x8-tile region
        int bid = blockIdx.x;
        int xc = bid & 7, ii = bid >> 3;          // ii 0..127
        int by = (xc >> 2) * 16 + (ii >> 3);      // 2 row-bands of 16
        int bx = (xc & 3) * 8 + (ii & 7);         // 4 col-bands of 8
        m0 = by * 128; n0 = bx * 128;
    }
    int w = threadIdx.x >> 6, lane = threadIdx.x & 63;
    int wm = (w >> 1) * 64, wn = (w & 1) * 64;
    int row16 = lane & 15, quad = lane >> 4;
    int lr  = lane >> 3;                  // staging row-within-8 (0..7)
    int lcs = ((lane & 7) ^ lr) << 3;     // pre-swizzled source col (u16)
    int xr  = (lane & 7) << 3;            // read-side col XOR (row16&7 == lane&7)
    f32x4 acc[4][4] = {};
    for (int k0 = 0; k0 < K; k0 += 64) {
        __syncthreads();
        // wave w stages rows [w*32, w*32+32) of both 128x64 tiles (8 DMAs)
#pragma unroll
        for (int j = 0; j < 4; ++j) {
            int rb = w * 32 + j * 8;
            gld_lds16(&A [(size_t)(m0 + rb + lr) * K + k0 + lcs], &As[rb][0]);
            gld_lds16(&BT[(size_t)(n0 + rb + lr) * K + k0 + lcs], &Bs[rb][0]);
        }
        __syncthreads();
        bf16x8 af[4][2], bfr[4][2];
#pragma unroll
        for (int i = 0; i < 4; ++i)
#pragma unroll
            for (int ks = 0; ks < 2; ++ks) {
                af[i][ks]  = *(const bf16x8*)&As[wm + i * 16 + row16][(ks * 32 + quad * 8) ^ xr];
                bfr[i][ks] = *(const bf16x8*)&Bs[wn + i * 16 + row16][(ks * 32 + quad * 8) ^ xr];
            }
#pragma unroll
        for (int mi = 0; mi < 4; ++mi)
#pragma unroll
            for (int ni = 0; ni < 4; ++ni)
#pragma unroll
                for (int ks = 0; ks < 2; ++ks)
                    acc[mi][ni] = __builtin_amdgcn_mfma_f32_16x16x32_bf16(
                            af[mi][ks], bfr[ni][ks], acc[mi][ni], 0, 0, 0);
    }
#pragma unroll
    for (int mi = 0; mi < 4; ++mi) {
#pragma unroll
        for (int ni = 0; ni < 4; ++ni) {
            int gcol = n0 + wn + ni * 16 + row16;
            float bv = bias[gcol];
#pragma unroll
            for (int i = 0; i < 4; ++i) {
                int grow = m0 + wm + mi * 16 + quad * 4 + i;
                float vv = acc[mi][ni][i] + bv;
                if (EPI == 1) {
                    vv += res[(size_t)grow * N + gcol];
                    ((float*)Cv)[(size_t)grow * N + gcol] = vv;
                } else {
                    if (EPI == 2)
                        vv = vv * 0.5f * (1.0f + erff(vv * 0.70710678118654752f));
                    ((u16*)Cv)[(size_t)grow * N + gcol] = f2b(vv);
                }
            }
        }
    }
}

// ---------------- QK RMSNorm + partial RoPE (q,k only), u32-vectorized -----
// One wave per (b,s,h). Lane l holds dims (2l, 2l+1) as one u32.
// RoPE: out[2j]=x0[j]c-x1[j]s, out[2j+1]=x1[j]c+x0[j]s, x0[j]=dim j,
// x1[j]=dim 16+j  -> lanes 0..15 produce their pair via 4 shuffles.
__global__ __launch_bounds__(256) void qk_rope(const u32* __restrict__ qkv32,
        const float* __restrict__ qn_w, const float* __restrict__ kn_w,
        const float* __restrict__ freqs,
        u32* __restrict__ q32, u32* __restrict__ k32) {
    int w = threadIdx.x >> 6, lane = threadIdx.x & 63;
    int unit = blockIdx.x * 4 + w;           // b*S*H + s*H + h
    int h = unit & (H_ - 1);
    int s = (unit >> 4) & (S_ - 1);
    int b = unit >> 15;
    size_t inbase  = (size_t)(b * S_ + s) * (3 * D_ / 2) + h * (HD_ / 2);
    size_t outbase = ((size_t)((b * H_ + h) * S_) + s) * (HD_ / 2);
    float fc = 0.f, fs = 0.f;
    if (lane < 16) {
        fc = freqs[(s * 16 + lane) * 2];
        fs = freqs[(s * 16 + lane) * 2 + 1];
    }
#pragma unroll
    for (int part = 0; part < 2; ++part) {   // 0: q, 1: k
        const float* nw = part ? kn_w : qn_w;
        u32 wv = qkv32[inbase + part * (D_ / 2) + lane];
        float a0 = b2f((u16)(wv & 0xffffu));
        float a1 = b2f((u16)(wv >> 16));
        float ss = wave_sum(a0 * a0 + a1 * a1);
        float inv = rsqrtf(ss * (1.f / HD_) + EPS_);
        float2 nwp = *(const float2*)&nw[2 * lane];
        float n0 = a0 * inv * nwp.x;
        float n1 = a1 * inv * nwp.y;
        // gather x0[j]=dim j (lane j>>1, parity j&1), x1[j]=dim 16+j
        float e0 = __shfl(n0, lane >> 1), e1 = __shfl(n1, lane >> 1);
        float o0 = __shfl(n0, 8 + (lane >> 1)), o1 = __shfl(n1, 8 + (lane >> 1));
        float x0 = (lane & 1) ? e1 : e0;
        float x1 = (lane & 1) ? o1 : o0;
        float rv0 = x0 * fc - x1 * fs;
        float rv1 = x1 * fc + x0 * fs;
        float w0 = (lane < 16) ? rv0 : n0;
        float w1 = (lane < 16) ? rv1 : n1;
        u32* dst = part ? k32 : q32;
        dst[outbase + lane] = (u32)f2b(w0) | ((u32)f2b(w1) << 16);
    }
}

// -------- V transpose: qkv V-part [b][s][h][d] -> vt [b][h][d][s] ----------
__global__ __launch_bounds__(256) void v_transpose(const u32* __restrict__ qkv32,
                                                   u32* __restrict__ vt32) {
    __shared__ u32 tile[64][17];
    int bh = blockIdx.z; int b = bh >> 4, h = bh & 15;
    int s0 = blockIdx.x * 64, d0 = blockIdx.y * 32;
    int tid = threadIdx.x;
    int rr = tid >> 4, cc = tid & 15;          // rr 0..15, cc 0..15 (u32 cols)
#pragma unroll
    for (int i = 0; i < 4; ++i) {
        int s = s0 + rr + i * 16;
        tile[rr + i * 16][cc] =
            qkv32[(size_t)(b * S_ + s) * (3 * D_ / 2) + (2 * D_ + h * HD_ + d0) / 2 + cc];
    }
    __syncthreads();
    int dr = tid & 31, sc = tid >> 5;          // dr 0..31, sc 0..7
#pragma unroll
    for (int i = 0; i < 4; ++i) {
        int s2 = sc + i * 8;                   // s-pair index 0..31
        u32 w0 = tile[2 * s2][dr >> 1];
        u32 w1 = tile[2 * s2 + 1][dr >> 1];
        u32 h0 = (dr & 1) ? (w0 >> 16) : (w0 & 0xffffu);
        u32 h1 = (dr & 1) ? (w1 >> 16) : (w1 & 0xffffu);
        vt32[((size_t)bh * HD_ + d0 + dr) * (S_ / 2) + (s0 >> 1) + s2] = h0 | (h1 << 16);
    }
}

// ---------------- MFMA sliding-window causal flash attention ---------------
// R16: spill-proof prefetch.  One kreg/vreg set; staging writes them to LDS,
// then (after the barrier) unconditionally loads tile min(t+1,g); the loads
// fly under QK/softmax/PV.  All defs/uses straight-line -> register-resident.
__global__ __launch_bounds__(256) void attn_mfma(
        const u16* __restrict__ q, const u16* __restrict__ k,
        const u16* __restrict__ vt, u16* __restrict__ y) {
    __shared__ __align__(16) u16 Ks [64][136];   // 272B rows: 68-word stride
    __shared__ __align__(16) u16 Vts[128][72];   // 144B rows: 36-word stride
    __shared__ __align__(16) u16 Ps [4][16][72];
    int g  = blockIdx.x & (S_ / 64 - 1);   // 0..31
    int bh = blockIdx.x >> 5;              // 0..31
    int qbase = g * 64;
    size_t kvbase = (size_t)bh * S_ * HD_;
    size_t vtbase = (size_t)bh * HD_ * S_;
    int w = threadIdx.x >> 6, lane = threadIdx.x & 63;
    int col16 = lane & 15, quad = lane >> 4;
    int q0w = qbase + w * 16;
    bf16x8 af[4];
#pragma unroll
    for (int kb = 0; kb < 4; ++kb)
        af[kb] = *(const bf16x8*)&q[kvbase + (size_t)(q0w + col16) * HD_ + kb * 32 + quad * 8];
    f32x4 oacc[8] = {};
    float mrow[4], lrow[4];
#pragma unroll
    for (int i = 0; i < 4; ++i) { mrow[i] = -1e38f; lrow[i] = 0.f; }
    int t0 = g >= 4 ? g - 4 : 0;
    int tid = threadIdx.x;
    int kr = tid >> 2, kc = (tid & 3) * 32;
    int vr = tid >> 1, vc = (tid & 1) * 32;
    uint4 kreg[4], vreg[4];
    {
        const u16* kg = &k[kvbase + (size_t)(t0 * 64 + kr) * HD_ + kc];
        const u16* vg = &vt[vtbase + (size_t)vr * S_ + t0 * 64 + vc];
#pragma unroll
        for (int i = 0; i < 4; ++i) {
            kreg[i] = *(const uint4*)&kg[i * 8];
            vreg[i] = *(const uint4*)&vg[i * 8];
        }
    }
    for (int t = t0; t <= g; ++t) {
        __syncthreads();
#pragma unroll
        for (int i = 0; i < 4; ++i) {
            *(uint4*)&Ks[kr][kc + i * 8]  = kreg[i];
            *(uint4*)&Vts[vr][vc + i * 8] = vreg[i];
        }
        __syncthreads();
        {   // unconditional clamped prefetch of next tile (post-barrier issue)
            int tn = (t < g) ? t + 1 : t;
            const u16* kg = &k[kvbase + (size_t)(tn * 64 + kr) * HD_ + kc];
            const u16* vg = &vt[vtbase + (size_t)vr * S_ + tn * 64 + vc];
#pragma unroll
            for (int i = 0; i < 4; ++i) {
                kreg[i] = *(const uint4*)&kg[i * 8];
                vreg[i] = *(const uint4*)&vg[i * 8];
            }
        }
        f32x4 sacc[4] = {};
#pragma unroll
        for (int ks = 0; ks < 4; ++ks)
#pragma unroll
            for (int kb = 0; kb < 4; ++kb) {
                bf16x8 bf = *(const bf16x8*)&Ks[ks * 16 + col16][kb * 32 + quad * 8];
                sacc[ks] = __builtin_amdgcn_mfma_f32_16x16x32_bf16(af[kb], bf, sacc[ks], 0, 0, 0);
            }
        float pm[4][4];
        float tmax[4] = {-3e38f, -3e38f, -3e38f, -3e38f};
#pragma unroll
        for (int ks = 0; ks < 4; ++ks) {
            int jg = t * 64 + ks * 16 + col16;
#pragma unroll
            for (int i = 0; i < 4; ++i) {
                int qi = q0w + quad * 4 + i;
                bool valid = (jg <= qi) && (qi - jg < WIN_);
                float sv = valid ? sacc[ks][i] * SCALE_ : -3e38f;
                pm[ks][i] = sv;
                tmax[i] = fmaxf(tmax[i], sv);
            }
        }
#pragma unroll
        for (int off = 8; off >= 1; off >>= 1)
#pragma unroll
            for (int i = 0; i < 4; ++i)
                tmax[i] = fmaxf(tmax[i], __shfl_xor(tmax[i], off));
        float alpha[4], psum[4];
#pragma unroll
        for (int i = 0; i < 4; ++i) {
            float mnew = fmaxf(mrow[i], tmax[i]);
            alpha[i] = __expf(mrow[i] - mnew);
            mrow[i] = mnew;
            psum[i] = 0.f;
        }
#pragma unroll
        for (int ks = 0; ks < 4; ++ks)
#pragma unroll
            for (int i = 0; i < 4; ++i) {
                float p = __expf(pm[ks][i] - mrow[i]);
                psum[i] += p;
                Ps[w][quad * 4 + i][ks * 16 + col16] = f2b(p);
            }
#pragma unroll
        for (int off = 8; off >= 1; off >>= 1)
#pragma unroll
            for (int i = 0; i < 4; ++i)
                psum[i] += __shfl_xor(psum[i], off);
#pragma unroll
        for (int i = 0; i < 4; ++i)
            lrow[i] = lrow[i] * alpha[i] + psum[i];
#pragma unroll
        for (int ns = 0; ns < 8; ++ns)
#pragma unroll
            for (int i = 0; i < 4; ++i)
                oacc[ns][i] *= alpha[i];
#pragma unroll
        for (int c = 0; c < 2; ++c) {
            bf16x8 pf = *(const bf16x8*)&Ps[w][col16][c * 32 + quad * 8];
#pragma unroll
            for (int ns = 0; ns < 8; ++ns) {
                bf16x8 vf = *(const bf16x8*)&Vts[ns * 16 + col16][c * 32 + quad * 8];
                oacc[ns] = __builtin_amdgcn_mfma_f32_16x16x32_bf16(pf, vf, oacc[ns], 0, 0, 0);
            }
        }
    }
    int b = bh >> 4, hh = bh & 15;
#pragma unroll
    for (int i = 0; i < 4; ++i) {
        int qi = q0w + quad * 4 + i;
        float invl = 1.f / lrow[i];
        size_t ob = (size_t)(b * S_ + qi) * D_ + hh * HD_;
#pragma unroll
        for (int ns = 0; ns < 8; ++ns)
            y[ob + ns * 16 + col16] = f2b(oacc[ns][i] * invl);
    }
}

// ---------------------------- host orchestration ---------------------------
extern "C" void kernel_launch(void* const* d_in, const int* in_sizes, int n_in,
                              void* d_out, int out_size, void* d_ws, size_t ws_size,
                              hipStream_t stream) {
    const float* x      = (const float*)d_in[0];
    const float* freqs  = (const float*)d_in[1];
    // d_in[2] = mask (unused; computed analytically)
    const float* wqkv_w = (const float*)d_in[3];
    const float* wqkv_b = (const float*)d_in[4];
    const float* wo_w   = (const float*)d_in[5];
    const float* wo_b   = (const float*)d_in[6];
    const float* qn_w   = (const float*)d_in[7];
    const float* kn_w   = (const float*)d_in[8];
    const float* aln_w  = (const float*)d_in[9];
    const float* aln_b  = (const float*)d_in[10];
    const float* fln_w  = (const float*)d_in[11];
    const float* fln_b  = (const float*)d_in[12];
    const float* w1_w   = (const float*)d_in[13];
    const float* w1_b   = (const float*)d_in[14];
    const float* w2_w   = (const float*)d_in[15];
    const float* w2_b   = (const float*)d_in[16];
    float* out = (float*)d_out;

    char* ws = (char*)d_ws;
    size_t off = 0;
    auto alloc = [&](size_t bytes) { char* p = ws + off; off += (bytes + 255) & ~(size_t)255; return (u16*)p; };
    const size_t E = sizeof(u16);
    u16* wt_qkv = alloc((size_t)D_ * 3 * D_ * E);       // bf16 [6144,2048]
    u16* wt_wo  = alloc((size_t)D_ * D_ * E);           // bf16 [2048,2048]
    u16* wt_w1  = alloc((size_t)D_ * FF_ * E);          // bf16 [4096,2048]
    u16* wt_w2  = alloc((size_t)FF_ * D_ * E);          // bf16 [2048,4096]
    u16* nx     = alloc((size_t)B_ * S_ * D_ * E);      // bf16; reused as y
    u16* f      = alloc((size_t)B_ * S_ * D_ * E);      // bf16
    u16* qkv    = alloc((size_t)B_ * S_ * 3 * D_ * E);  // bf16; reused as tmid
    u16* qb     = alloc((size_t)B_ * S_ * D_ * E);      // bf16 [b][h][s][d]
    u16* kb     = alloc((size_t)B_ * S_ * D_ * E);      // bf16 [b][h][s][d]
    u16* vtb    = alloc((size_t)B_ * S_ * D_ * E);      // bf16 [b][h][d][s]
    u16* y    = nx;    // nx consumed by QKV GEMM before attention writes y
    u16* tmid = qkv;   // qkv consumed by qk_rope/v_transpose before FFN1
    float* h  = out;   // h lives in d_out

    if (off > ws_size) return;  // tripwire -> finite err signature

    const int M = B_ * S_;  // 4096

    transpose_k<<<dim3(3 * D_ / 64, D_ / 64), 256, 0, stream>>>(wqkv_w, wt_qkv, D_, 3 * D_);
    transpose_k<<<dim3(D_ / 64, D_ / 64),     256, 0, stream>>>(wo_w,   wt_wo,  D_, D_);
    transpose_k<<<dim3(FF_ / 64, D_ / 64),    256, 0, stream>>>(w1_w,   wt_w1,  D_, FF_);
    transpose_k<<<dim3(D_ / 64, FF_ / 64),    256, 0, stream>>>(w2_w,   wt_w2,  FF_, D_);

    ln_dual<<<M, 256, 0, stream>>>(x, aln_w, aln_b, fln_w, fln_b, nx, f);

    // QKV: proven R13 2D-grid path
    gemm_bt<0, 0><<<dim3(3 * D_ / 128, M / 128), 256, 0, stream>>>(
            nx, wt_qkv, wqkv_b, nullptr, qkv, M, 3 * D_, D_);

    qk_rope<<<B_ * S_ * H_ / 4, 256, 0, stream>>>((const u32*)qkv, qn_w, kn_w, freqs, (u32*)qb, (u32*)kb);
    v_transpose<<<dim3(S_ / 64, HD_ / 32, B_ * H_), 256, 0, stream>>>((const u32*)qkv, (u32*)vtb);

    attn_mfma<<<B_ * H_ * (S_ / 64), 256, 0, stream>>>(qb, kb, vtb, y);

    // FFN1: 16x8 XCD-supertile remap (grid 1024)
    gemm_bt<2, 2><<<(FF_ / 128) * (M / 128), 256, 0, stream>>>(
            f, wt_w1, w1_b, nullptr, tmid, M, FF_, D_);

    // WO/W2: 8x8 XCD-supertile remap (grid 512)
    gemm_bt<1, 1><<<(D_ / 128) * (M / 128), 256, 0, stream>>>(
            y, wt_wo, wo_b, x, h, M, D_, D_);

    gemm_bt<1, 1><<<(D_ / 128) * (M / 128), 256, 0, stream>>>(
            tmid, wt_w2, w2_b, h, out, M, D_, FF_);
}

// Round 11
// 634.706 us; speedup vs baseline: 1.0843x; 1.0843x over previous
//
#include <hip/hip_runtime.h>

// TransformerBlock on MI355X (gfx950). External dtype: FP32. Internals bf16.
//   transpose_k: W fp32 [R][C] -> bf16 [C][R]  (64x64 tiles, u32 stores)
//   ln_dual:     nx = LN(x,attn_ln), f = LN(x,ffn_ln)
//   gemm<0,0>:   qkv = nx @ Wqkv + b          (128^2, BK=64, swizzled LDS, 2D grid)
//   qk_rope:     RMSNorm + RoPE(first 32 dims) on q,k   (u32-vectorized)
//   v_transpose: V part of qkv -> vt [b][h][dim][key]
//   attn_mfma:   sliding-window(256) causal flash attention, MFMA (proven body)
//   gemm<2,2>:   tmid = gelu_exact(f @ W1 + b1)   (16x8 XCD supertile)
//   gemm<1,1>:   h = x + y @ Wo + b           (fp32, in d_out; 8x8 XCD supertile)
//   gemm<1,1>:   out = h + tmid @ W2 + b2     (8x8 XCD supertile)
//
// R16 -> R17: attention prefetch abandoned permanently - two attempts (R11
// cond, R16 uncond straight-line) both spilled (VGPR_Count pinned at 80 by
// the compiler's occupancy target; +32 cross-barrier regs -> scratch, 340MB
// traffic, MfmaUtil 3%).  Attention reverted to the proven direct-staging
// body.  FFN1 keeps the 16x8 XCD remap (only new piece; attributable vs
// R15's 649.4us: R16 arithmetic suggests it gained ~10us).

typedef unsigned short u16;
typedef unsigned int   u32;
typedef __bf16 bf16x8 __attribute__((ext_vector_type(8)));
typedef float  f32x4  __attribute__((ext_vector_type(4)));
typedef __attribute__((address_space(3))) u32 as3_u32;
typedef __attribute__((address_space(1))) u32 as1_u32;

#define B_    2
#define S_    2048
#define D_    2048
#define H_    16
#define HD_   128
#define FF_   4096
#define WIN_  256
#define EPS_  1e-5f
#define SCALE_ 0.08838834764831845f  // 1/sqrt(128)

__device__ __forceinline__ float b2f(u16 u) {
    return __uint_as_float(((u32)u) << 16);
}
__device__ __forceinline__ u16 f2b(float f) {
    u32 u = __float_as_uint(f);
    u32 r = (u + 0x7fffu + ((u >> 16) & 1u)) >> 16;  // RNE
    return (u16)r;
}
__device__ __forceinline__ float wave_sum(float v) {
#pragma unroll
    for (int o = 32; o > 0; o >>= 1) v += __shfl_xor(v, o);
    return v;
}
// async 16B/lane global->LDS; lds base must be wave-uniform, lane i lands at
// base + i*16 (m97 pattern).
__device__ __forceinline__ void gld_lds16(const u16* g, u16* l) {
    __builtin_amdgcn_global_load_lds((const as1_u32*)g, (as3_u32*)l, 16, 0, 0);
}

// -------- weight transpose + cast: in fp32 [R][C] -> out bf16 [C][R] -------
// 64x64 tile; write phase packs row-pairs into u32 (contiguous along R).
__global__ __launch_bounds__(256) void transpose_k(const float* __restrict__ in,
                                                   u16* __restrict__ out,
                                                   int R, int C) {
    __shared__ float tile[64][65];
    int t = threadIdx.x;
    int r0 = blockIdx.y * 64, c0 = blockIdx.x * 64;
    int rr = t >> 2;              // 0..63
    int cb = (t & 3) * 16;        // 0,16,32,48
    const float* src = &in[(size_t)(r0 + rr) * C + c0 + cb];
#pragma unroll
    for (int j = 0; j < 16; j += 4) {
        float4 v = *(const float4*)&src[j];
        tile[rr][cb + j]     = v.x; tile[rr][cb + j + 1] = v.y;
        tile[rr][cb + j + 2] = v.z; tile[rr][cb + j + 3] = v.w;
    }
    __syncthreads();
    int wq = t & 31;              // row-pair 0..31 (rows 2wq, 2wq+1)
    int ch = t >> 5;              // 0..7
#pragma unroll
    for (int i = 0; i < 8; ++i) {
        int c = ch * 8 + i;       // 0..63
        u32 lo = (u32)f2b(tile[2 * wq][c]);
        u32 hi = (u32)f2b(tile[2 * wq + 1][c]);
        ((u32*)out)[(((size_t)(c0 + c) * R) >> 1) + (r0 >> 1) + wq] = lo | (hi << 16);
    }
}

// ---------- dual LayerNorm: fp32 x -> bf16 nx, f (one pass) ----------------
__global__ __launch_bounds__(256) void ln_dual(const float* __restrict__ x,
        const float* __restrict__ aw, const float* __restrict__ ab,
        const float* __restrict__ fw, const float* __restrict__ fb,
        u16* __restrict__ nx, u16* __restrict__ f) {
    int row = blockIdx.x;                // 0..B*S-1
    const float* xr = x + (size_t)row * D_;
    int base = threadIdx.x * 8;
    float4 xa = *(const float4*)&xr[base];
    float4 xb = *(const float4*)&xr[base + 4];
    float xv[8] = {xa.x, xa.y, xa.z, xa.w, xb.x, xb.y, xb.z, xb.w};
    float s = 0.f, s2 = 0.f;
#pragma unroll
    for (int i = 0; i < 8; ++i) { s += xv[i]; s2 += xv[i] * xv[i]; }
    s = wave_sum(s); s2 = wave_sum(s2);
    __shared__ float r1[4], r2[4];
    int w = threadIdx.x >> 6;
    if ((threadIdx.x & 63) == 0) { r1[w] = s; r2[w] = s2; }
    __syncthreads();
    float ts  = r1[0] + r1[1] + r1[2] + r1[3];
    float ts2 = r2[0] + r2[1] + r2[2] + r2[3];
    float mean = ts * (1.f / D_);
    float var  = ts2 * (1.f / D_) - mean * mean;
    float inv  = rsqrtf(var + EPS_);
    float4 wa0 = *(const float4*)&aw[base], wa1 = *(const float4*)&aw[base + 4];
    float4 ba0 = *(const float4*)&ab[base], ba1 = *(const float4*)&ab[base + 4];
    float4 wf0 = *(const float4*)&fw[base], wf1 = *(const float4*)&fw[base + 4];
    float4 bf0 = *(const float4*)&fb[base], bf1 = *(const float4*)&fb[base + 4];
    float wav[8] = {wa0.x, wa0.y, wa0.z, wa0.w, wa1.x, wa1.y, wa1.z, wa1.w};
    float bav[8] = {ba0.x, ba0.y, ba0.z, ba0.w, ba1.x, ba1.y, ba1.z, ba1.w};
    float wfv[8] = {wf0.x, wf0.y, wf0.z, wf0.w, wf1.x, wf1.y, wf1.z, wf1.w};
    float bfv[8] = {bf0.x, bf0.y, bf0.z, bf0.w, bf1.x, bf1.y, bf1.z, bf1.w};
    union { uint4 v; u16 s[8]; } o1, o2;
#pragma unroll
    for (int i = 0; i < 8; ++i) {
        float t = (xv[i] - mean) * inv;
        o1.s[i] = f2b(t * wav[i] + bav[i]);
        o2.s[i] = f2b(t * wfv[i] + bfv[i]);
    }
    *(uint4*)&nx[(size_t)row * D_ + base] = o1.v;
    *(uint4*)&f [(size_t)row * D_ + base] = o2.v;
}

// ---------------- MFMA GEMM: 128^2 tile, BK=64, swizzled LDS ---------------
// m97 2-phase structure with BK=64 + XOR LDS swizzle (QKV 99-102us @ ~48%
// MfmaUtil, conflicts 0).
// SWZ=0: plain 2D grid.  SWZ=1: WO/W2 map (grid 512, 8 XCD supertiles of
// 8x8 tiles).  SWZ=2: FFN1 map (grid 1024, 8 XCDs as 2x4 bands of 16x8).
// EPI 0: bf16 out.  EPI 1: fp32 out, += fp32 residual.  EPI 2: bf16, GELU.
template <int EPI, int SWZ>
__global__ __launch_bounds__(256, 2) void gemm_bt(
        const u16* __restrict__ A, const u16* __restrict__ BT,
        const float* __restrict__ bias, const float* __restrict__ res,
        void* __restrict__ Cv, int M, int N, int K) {
    __shared__ __align__(16) u16 As[128][64];
    __shared__ __align__(16) u16 Bs[128][64];
    int m0, n0;
    if (SWZ == 0) {
        m0 = blockIdx.y * 128; n0 = blockIdx.x * 128;
    } else if (SWZ == 1) {
        // grid = 512: XCD xc owns the 8x8-tile supertile (xc>>1, xc&1)
        int bid = blockIdx.x;
        int xc = bid & 7, ii = bid >> 3;
        int by = (xc >> 1) * 8 + (ii >> 3);
        int bx = (xc & 1) * 8 + (ii & 7);
        m0 = by * 128; n0 = bx * 128;
    } else {
        // grid = 1024 (32x32 tiles): XCD xc owns a 16x8-tile region
        int bid = blockIdx.x;
        int xc = bid & 7, ii = bid >> 3;          // ii 0..127
        int by = (xc >> 2) * 16 + (ii >> 3);      // 2 row-bands of 16
        int bx = (xc & 3) * 8 + (ii & 7);         // 4 col-bands of 8
        m0 = by * 128; n0 = bx * 128;
    }
    int w = threadIdx.x >> 6, lane = threadIdx.x & 63;
    int wm = (w >> 1) * 64, wn = (w & 1) * 64;
    int row16 = lane & 15, quad = lane >> 4;
    int lr  = lane >> 3;                  // staging row-within-8 (0..7)
    int lcs = ((lane & 7) ^ lr) << 3;     // pre-swizzled source col (u16)
    int xr  = (lane & 7) << 3;            // read-side col XOR (row16&7 == lane&7)
    f32x4 acc[4][4] = {};
    for (int k0 = 0; k0 < K; k0 += 64) {
        __syncthreads();
        // wave w stages rows [w*32, w*32+32) of both 128x64 tiles (8 DMAs)
#pragma unroll
        for (int j = 0; j < 4; ++j) {
            int rb = w * 32 + j * 8;
            gld_lds16(&A [(size_t)(m0 + rb + lr) * K + k0 + lcs], &As[rb][0]);
            gld_lds16(&BT[(size_t)(n0 + rb + lr) * K + k0 + lcs], &Bs[rb][0]);
        }
        __syncthreads();
        bf16x8 af[4][2], bfr[4][2];
#pragma unroll
        for (int i = 0; i < 4; ++i)
#pragma unroll
            for (int ks = 0; ks < 2; ++ks) {
                af[i][ks]  = *(const bf16x8*)&As[wm + i * 16 + row16][(ks * 32 + quad * 8) ^ xr];
                bfr[i][ks] = *(const bf16x8*)&Bs[wn + i * 16 + row16][(ks * 32 + quad * 8) ^ xr];
            }
#pragma unroll
        for (int mi = 0; mi < 4; ++mi)
#pragma unroll
            for (int ni = 0; ni < 4; ++ni)
#pragma unroll
                for (int ks = 0; ks < 2; ++ks)
                    acc[mi][ni] = __builtin_amdgcn_mfma_f32_16x16x32_bf16(
                            af[mi][ks], bfr[ni][ks], acc[mi][ni], 0, 0, 0);
    }
#pragma unroll
    for (int mi = 0; mi < 4; ++mi) {
#pragma unroll
        for (int ni = 0; ni < 4; ++ni) {
            int gcol = n0 + wn + ni * 16 + row16;
            float bv = bias[gcol];
#pragma unroll
            for (int i = 0; i < 4; ++i) {
                int grow = m0 + wm + mi * 16 + quad * 4 + i;
                float vv = acc[mi][ni][i] + bv;
                if (EPI == 1) {
                    vv += res[(size_t)grow * N + gcol];
                    ((float*)Cv)[(size_t)grow * N + gcol] = vv;
                } else {
                    if (EPI == 2)
                        vv = vv * 0.5f * (1.0f + erff(vv * 0.70710678118654752f));
                    ((u16*)Cv)[(size_t)grow * N + gcol] = f2b(vv);
                }
            }
        }
    }
}

// ---------------- QK RMSNorm + partial RoPE (q,k only), u32-vectorized -----
// One wave per (b,s,h). Lane l holds dims (2l, 2l+1) as one u32.
// RoPE: out[2j]=x0[j]c-x1[j]s, out[2j+1]=x1[j]c+x0[j]s, x0[j]=dim j,
// x1[j]=dim 16+j  -> lanes 0..15 produce their pair via 4 shuffles.
__global__ __launch_bounds__(256) void qk_rope(const u32* __restrict__ qkv32,
        const float* __restrict__ qn_w, const float* __restrict__ kn_w,
        const float* __restrict__ freqs,
        u32* __restrict__ q32, u32* __restrict__ k32) {
    int w = threadIdx.x >> 6, lane = threadIdx.x & 63;
    int unit = blockIdx.x * 4 + w;           // b*S*H + s*H + h
    int h = unit & (H_ - 1);
    int s = (unit >> 4) & (S_ - 1);
    int b = unit >> 15;
    size_t inbase  = (size_t)(b * S_ + s) * (3 * D_ / 2) + h * (HD_ / 2);
    size_t outbase = ((size_t)((b * H_ + h) * S_) + s) * (HD_ / 2);
    float fc = 0.f, fs = 0.f;
    if (lane < 16) {
        fc = freqs[(s * 16 + lane) * 2];
        fs = freqs[(s * 16 + lane) * 2 + 1];
    }
#pragma unroll
    for (int part = 0; part < 2; ++part) {   // 0: q, 1: k
        const float* nw = part ? kn_w : qn_w;
        u32 wv = qkv32[inbase + part * (D_ / 2) + lane];
        float a0 = b2f((u16)(wv & 0xffffu));
        float a1 = b2f((u16)(wv >> 16));
        float ss = wave_sum(a0 * a0 + a1 * a1);
        float inv = rsqrtf(ss * (1.f / HD_) + EPS_);
        float2 nwp = *(const float2*)&nw[2 * lane];
        float n0 = a0 * inv * nwp.x;
        float n1 = a1 * inv * nwp.y;
        // gather x0[j]=dim j (lane j>>1, parity j&1), x1[j]=dim 16+j
        float e0 = __shfl(n0, lane >> 1), e1 = __shfl(n1, lane >> 1);
        float o0 = __shfl(n0, 8 + (lane >> 1)), o1 = __shfl(n1, 8 + (lane >> 1));
        float x0 = (lane & 1) ? e1 : e0;
        float x1 = (lane & 1) ? o1 : o0;
        float rv0 = x0 * fc - x1 * fs;
        float rv1 = x1 * fc + x0 * fs;
        float w0 = (lane < 16) ? rv0 : n0;
        float w1 = (lane < 16) ? rv1 : n1;
        u32* dst = part ? k32 : q32;
        dst[outbase + lane] = (u32)f2b(w0) | ((u32)f2b(w1) << 16);
    }
}

// -------- V transpose: qkv V-part [b][s][h][d] -> vt [b][h][d][s] ----------
__global__ __launch_bounds__(256) void v_transpose(const u32* __restrict__ qkv32,
                                                   u32* __restrict__ vt32) {
    __shared__ u32 tile[64][17];
    int bh = blockIdx.z; int b = bh >> 4, h = bh & 15;
    int s0 = blockIdx.x * 64, d0 = blockIdx.y * 32;
    int tid = threadIdx.x;
    int rr = tid >> 4, cc = tid & 15;          // rr 0..15, cc 0..15 (u32 cols)
#pragma unroll
    for (int i = 0; i < 4; ++i) {
        int s = s0 + rr + i * 16;
        tile[rr + i * 16][cc] =
            qkv32[(size_t)(b * S_ + s) * (3 * D_ / 2) + (2 * D_ + h * HD_ + d0) / 2 + cc];
    }
    __syncthreads();
    int dr = tid & 31, sc = tid >> 5;          // dr 0..31, sc 0..7
#pragma unroll
    for (int i = 0; i < 4; ++i) {
        int s2 = sc + i * 8;                   // s-pair index 0..31
        u32 w0 = tile[2 * s2][dr >> 1];
        u32 w1 = tile[2 * s2 + 1][dr >> 1];
        u32 h0 = (dr & 1) ? (w0 >> 16) : (w0 & 0xffffu);
        u32 h1 = (dr & 1) ? (w1 >> 16) : (w1 & 0xffffu);
        vt32[((size_t)bh * HD_ + d0 + dr) * (S_ / 2) + (s0 >> 1) + s2] = h0 | (h1 << 16);
    }
}

// ---------------- MFMA sliding-window causal flash attention ---------------
// Proven body: direct global->LDS staging, no register prefetch (R11/R16
// prefetch attempts both spilled - compiler pins VGPR at 80 for this kernel).
__global__ __launch_bounds__(256) void attn_mfma(
        const u16* __restrict__ q, const u16* __restrict__ k,
        const u16* __restrict__ vt, u16* __restrict__ y) {
    __shared__ __align__(16) u16 Ks [64][136];   // 272B rows: 68-word stride
    __shared__ __align__(16) u16 Vts[128][72];   // 144B rows: 36-word stride
    __shared__ __align__(16) u16 Ps [4][16][72];
    int g  = blockIdx.x & (S_ / 64 - 1);   // 0..31
    int bh = blockIdx.x >> 5;              // 0..31
    int qbase = g * 64;
    size_t kvbase = (size_t)bh * S_ * HD_;
    size_t vtbase = (size_t)bh * HD_ * S_;
    int w = threadIdx.x >> 6, lane = threadIdx.x & 63;
    int col16 = lane & 15, quad = lane >> 4;
    int q0w = qbase + w * 16;
    bf16x8 af[4];
#pragma unroll
    for (int kb = 0; kb < 4; ++kb)
        af[kb] = *(const bf16x8*)&q[kvbase + (size_t)(q0w + col16) * HD_ + kb * 32 + quad * 8];
    f32x4 oacc[8] = {};
    float mrow[4], lrow[4];
#pragma unroll
    for (int i = 0; i < 4; ++i) { mrow[i] = -1e38f; lrow[i] = 0.f; }
    int t0 = g >= 4 ? g - 4 : 0;
    int tid = threadIdx.x;
    int kr = tid >> 2, kc = (tid & 3) * 32;
    int vr = tid >> 1, vc = (tid & 1) * 32;
    for (int t = t0; t <= g; ++t) {
        __syncthreads();
        {
            const u16* kg = &k[kvbase + (size_t)(t * 64 + kr) * HD_ + kc];
#pragma unroll
            for (int i = 0; i < 4; ++i)
                *(uint4*)&Ks[kr][kc + i * 8] = *(const uint4*)&kg[i * 8];
            const u16* vg = &vt[vtbase + (size_t)vr * S_ + t * 64 + vc];
#pragma unroll
            for (int i = 0; i < 4; ++i)
                *(uint4*)&Vts[vr][vc + i * 8] = *(const uint4*)&vg[i * 8];
        }
        __syncthreads();
        f32x4 sacc[4] = {};
#pragma unroll
        for (int ks = 0; ks < 4; ++ks)
#pragma unroll
            for (int kb = 0; kb < 4; ++kb) {
                bf16x8 bf = *(const bf16x8*)&Ks[ks * 16 + col16][kb * 32 + quad * 8];
                sacc[ks] = __builtin_amdgcn_mfma_f32_16x16x32_bf16(af[kb], bf, sacc[ks], 0, 0, 0);
            }
        float pm[4][4];
        float tmax[4] = {-3e38f, -3e38f, -3e38f, -3e38f};
#pragma unroll
        for (int ks = 0; ks < 4; ++ks) {
            int jg = t * 64 + ks * 16 + col16;
#pragma unroll
            for (int i = 0; i < 4; ++i) {
                int qi = q0w + quad * 4 + i;
                bool valid = (jg <= qi) && (qi - jg < WIN_);
                float sv = valid ? sacc[ks][i] * SCALE_ : -3e38f;
                pm[ks][i] = sv;
                tmax[i] = fmaxf(tmax[i], sv);
            }
        }
#pragma unroll
        for (int off = 8; off >= 1; off >>= 1)
#pragma unroll
            for (int i = 0; i < 4; ++i)
                tmax[i] = fmaxf(tmax[i], __shfl_xor(tmax[i], off));
        float alpha[4], psum[4];
#pragma unroll
        for (int i = 0; i < 4; ++i) {
            float mnew = fmaxf(mrow[i], tmax[i]);
            alpha[i] = __expf(mrow[i] - mnew);
            mrow[i] = mnew;
            psum[i] = 0.f;
        }
#pragma unroll
        for (int ks = 0; ks < 4; ++ks)
#pragma unroll
            for (int i = 0; i < 4; ++i) {
                float p = __expf(pm[ks][i] - mrow[i]);
                psum[i] += p;
                Ps[w][quad * 4 + i][ks * 16 + col16] = f2b(p);
            }
#pragma unroll
        for (int off = 8; off >= 1; off >>= 1)
#pragma unroll
            for (int i = 0; i < 4; ++i)
                psum[i] += __shfl_xor(psum[i], off);
#pragma unroll
        for (int i = 0; i < 4; ++i)
            lrow[i] = lrow[i] * alpha[i] + psum[i];
#pragma unroll
        for (int ns = 0; ns < 8; ++ns)
#pragma unroll
            for (int i = 0; i < 4; ++i)
                oacc[ns][i] *= alpha[i];
#pragma unroll
        for (int c = 0; c < 2; ++c) {
            bf16x8 pf = *(const bf16x8*)&Ps[w][col16][c * 32 + quad * 8];
#pragma unroll
            for (int ns = 0; ns < 8; ++ns) {
                bf16x8 vf = *(const bf16x8*)&Vts[ns * 16 + col16][c * 32 + quad * 8];
                oacc[ns] = __builtin_amdgcn_mfma_f32_16x16x32_bf16(pf, vf, oacc[ns], 0, 0, 0);
            }
        }
    }
    int b = bh >> 4, hh = bh & 15;
#pragma unroll
    for (int i = 0; i < 4; ++i) {
        int qi = q0w + quad * 4 + i;
        float invl = 1.f / lrow[i];
        size_t ob = (size_t)(b * S_ + qi) * D_ + hh * HD_;
#pragma unroll
        for (int ns = 0; ns < 8; ++ns)
            y[ob + ns * 16 + col16] = f2b(oacc[ns][i] * invl);
    }
}

// ---------------------------- host orchestration ---------------------------
extern "C" void kernel_launch(void* const* d_in, const int* in_sizes, int n_in,
                              void* d_out, int out_size, void* d_ws, size_t ws_size,
                              hipStream_t stream) {
    const float* x      = (const float*)d_in[0];
    const float* freqs  = (const float*)d_in[1];
    // d_in[2] = mask (unused; computed analytically)
    const float* wqkv_w = (const float*)d_in[3];
    const float* wqkv_b = (const float*)d_in[4];
    const float* wo_w   = (const float*)d_in[5];
    const float* wo_b   = (const float*)d_in[6];
    const float* qn_w   = (const float*)d_in[7];
    const float* kn_w   = (const float*)d_in[8];
    const float* aln_w  = (const float*)d_in[9];
    const float* aln_b  = (const float*)d_in[10];
    const float* fln_w  = (const float*)d_in[11];
    const float* fln_b  = (const float*)d_in[12];
    const float* w1_w   = (const float*)d_in[13];
    const float* w1_b   = (const float*)d_in[14];
    const float* w2_w   = (const float*)d_in[15];
    const float* w2_b   = (const float*)d_in[16];
    float* out = (float*)d_out;

    char* ws = (char*)d_ws;
    size_t off = 0;
    auto alloc = [&](size_t bytes) { char* p = ws + off; off += (bytes + 255) & ~(size_t)255; return (u16*)p; };
    const size_t E = sizeof(u16);
    u16* wt_qkv = alloc((size_t)D_ * 3 * D_ * E);       // bf16 [6144,2048]
    u16* wt_wo  = alloc((size_t)D_ * D_ * E);           // bf16 [2048,2048]
    u16* wt_w1  = alloc((size_t)D_ * FF_ * E);          // bf16 [4096,2048]
    u16* wt_w2  = alloc((size_t)FF_ * D_ * E);          // bf16 [2048,4096]
    u16* nx     = alloc((size_t)B_ * S_ * D_ * E);      // bf16; reused as y
    u16* f      = alloc((size_t)B_ * S_ * D_ * E);      // bf16
    u16* qkv    = alloc((size_t)B_ * S_ * 3 * D_ * E);  // bf16; reused as tmid
    u16* qb     = alloc((size_t)B_ * S_ * D_ * E);      // bf16 [b][h][s][d]
    u16* kb     = alloc((size_t)B_ * S_ * D_ * E);      // bf16 [b][h][s][d]
    u16* vtb    = alloc((size_t)B_ * S_ * D_ * E);      // bf16 [b][h][d][s]
    u16* y    = nx;    // nx consumed by QKV GEMM before attention writes y
    u16* tmid = qkv;   // qkv consumed by qk_rope/v_transpose before FFN1
    float* h  = out;   // h lives in d_out

    if (off > ws_size) return;  // tripwire -> finite err signature

    const int M = B_ * S_;  // 4096

    transpose_k<<<dim3(3 * D_ / 64, D_ / 64), 256, 0, stream>>>(wqkv_w, wt_qkv, D_, 3 * D_);
    transpose_k<<<dim3(D_ / 64, D_ / 64),     256, 0, stream>>>(wo_w,   wt_wo,  D_, D_);
    transpose_k<<<dim3(FF_ / 64, D_ / 64),    256, 0, stream>>>(w1_w,   wt_w1,  D_, FF_);
    transpose_k<<<dim3(D_ / 64, FF_ / 64),    256, 0, stream>>>(w2_w,   wt_w2,  FF_, D_);

    ln_dual<<<M, 256, 0, stream>>>(x, aln_w, aln_b, fln_w, fln_b, nx, f);

    // QKV: proven R13 2D-grid path
    gemm_bt<0, 0><<<dim3(3 * D_ / 128, M / 128), 256, 0, stream>>>(
            nx, wt_qkv, wqkv_b, nullptr, qkv, M, 3 * D_, D_);

    qk_rope<<<B_ * S_ * H_ / 4, 256, 0, stream>>>((const u32*)qkv, qn_w, kn_w, freqs, (u32*)qb, (u32*)kb);
    v_transpose<<<dim3(S_ / 64, HD_ / 32, B_ * H_), 256, 0, stream>>>((const u32*)qkv, (u32*)vtb);

    attn_mfma<<<B_ * H_ * (S_ / 64), 256, 0, stream>>>(qb, kb, vtb, y);

    // FFN1: 16x8 XCD-supertile remap (grid 1024)
    gemm_bt<2, 2><<<(FF_ / 128) * (M / 128), 256, 0, stream>>>(
            f, wt_w1, w1_b, nullptr, tmid, M, FF_, D_);

    // WO/W2: 8x8 XCD-supertile remap (grid 512)
    gemm_bt<1, 1><<<(D_ / 128) * (M / 128), 256, 0, stream>>>(
            y, wt_wo, wo_b, x, h, M, D_, D_);

    gemm_bt<1, 1><<<(D_ / 128) * (M / 128), 256, 0, stream>>>(
            tmid, wt_w2, w2_b, h, out, M, D_, FF_);
}

// Round 12
// 634.167 us; speedup vs baseline: 1.0852x; 1.0008x over previous
//
#include <hip/hip_runtime.h>

// TransformerBlock on MI355X (gfx950). External dtype: FP32. Internals bf16.
//   transpose_k: W fp32 [R][C] -> bf16 [C][R]  (64x64 tiles, u32 stores)
//   ln_dual:     nx = LN(x,attn_ln), f = LN(x,ffn_ln)
//   gemm<0,0>:   qkv = nx @ Wqkv + b          (128^2, BK=64, swizzled LDS, 2D grid)
//   qk_rope:     RMSNorm + RoPE(first 32 dims) on q,k   (u32-vectorized)
//   v_transpose: V part of qkv -> vt [b][h][dim][key]
//   attn_mfma:   sliding-window(256) causal flash attention, MFMA, QBLK=128
//   gemm<2,2>:   tmid = gelu_exact(f @ W1 + b1)   (16x8 XCD supertile)
//   gemm<1,1>:   h = x + y @ Wo + b           (fp32, in d_out; 8x8 XCD supertile)
//   gemm<1,1>:   out = h + tmid @ W2 + b2     (8x8 XCD supertile)
//
// R17 -> R18: attention q-tile doubled 64->128 rows (8 waves, 512 threads).
// Rationale: cross-barrier pipelining is closed (2 spill failures; compiler
// pins VGPR), so amortize instead - staging events per unit work halve
// (5120 -> ~2870 block-tiles), compute per staging stall doubles, and the
// grid becomes 512 blocks = exactly 2/CU (LDS 54.3KB -> 2 resident, no
// tail).  Per-thread register shapes unchanged (no new spill risk); K/V
// LDS layouts and read patterns byte-identical; only staging split and
// Ps[8] differ.  Everything else identical to R17 (634.7us best).

typedef unsigned short u16;
typedef unsigned int   u32;
typedef __bf16 bf16x8 __attribute__((ext_vector_type(8)));
typedef float  f32x4  __attribute__((ext_vector_type(4)));
typedef __attribute__((address_space(3))) u32 as3_u32;
typedef __attribute__((address_space(1))) u32 as1_u32;

#define B_    2
#define S_    2048
#define D_    2048
#define H_    16
#define HD_   128
#define FF_   4096
#define WIN_  256
#define EPS_  1e-5f
#define SCALE_ 0.08838834764831845f  // 1/sqrt(128)

__device__ __forceinline__ float b2f(u16 u) {
    return __uint_as_float(((u32)u) << 16);
}
__device__ __forceinline__ u16 f2b(float f) {
    u32 u = __float_as_uint(f);
    u32 r = (u + 0x7fffu + ((u >> 16) & 1u)) >> 16;  // RNE
    return (u16)r;
}
__device__ __forceinline__ float wave_sum(float v) {
#pragma unroll
    for (int o = 32; o > 0; o >>= 1) v += __shfl_xor(v, o);
    return v;
}
// async 16B/lane global->LDS; lds base must be wave-uniform, lane i lands at
// base + i*16 (m97 pattern).
__device__ __forceinline__ void gld_lds16(const u16* g, u16* l) {
    __builtin_amdgcn_global_load_lds((const as1_u32*)g, (as3_u32*)l, 16, 0, 0);
}

// -------- weight transpose + cast: in fp32 [R][C] -> out bf16 [C][R] -------
// 64x64 tile; write phase packs row-pairs into u32 (contiguous along R).
__global__ __launch_bounds__(256) void transpose_k(const float* __restrict__ in,
                                                   u16* __restrict__ out,
                                                   int R, int C) {
    __shared__ float tile[64][65];
    int t = threadIdx.x;
    int r0 = blockIdx.y * 64, c0 = blockIdx.x * 64;
    int rr = t >> 2;              // 0..63
    int cb = (t & 3) * 16;        // 0,16,32,48
    const float* src = &in[(size_t)(r0 + rr) * C + c0 + cb];
#pragma unroll
    for (int j = 0; j < 16; j += 4) {
        float4 v = *(const float4*)&src[j];
        tile[rr][cb + j]     = v.x; tile[rr][cb + j + 1] = v.y;
        tile[rr][cb + j + 2] = v.z; tile[rr][cb + j + 3] = v.w;
    }
    __syncthreads();
    int wq = t & 31;              // row-pair 0..31 (rows 2wq, 2wq+1)
    int ch = t >> 5;              // 0..7
#pragma unroll
    for (int i = 0; i < 8; ++i) {
        int c = ch * 8 + i;       // 0..63
        u32 lo = (u32)f2b(tile[2 * wq][c]);
        u32 hi = (u32)f2b(tile[2 * wq + 1][c]);
        ((u32*)out)[(((size_t)(c0 + c) * R) >> 1) + (r0 >> 1) + wq] = lo | (hi << 16);
    }
}

// ---------- dual LayerNorm: fp32 x -> bf16 nx, f (one pass) ----------------
__global__ __launch_bounds__(256) void ln_dual(const float* __restrict__ x,
        const float* __restrict__ aw, const float* __restrict__ ab,
        const float* __restrict__ fw, const float* __restrict__ fb,
        u16* __restrict__ nx, u16* __restrict__ f) {
    int row = blockIdx.x;                // 0..B*S-1
    const float* xr = x + (size_t)row * D_;
    int base = threadIdx.x * 8;
    float4 xa = *(const float4*)&xr[base];
    float4 xb = *(const float4*)&xr[base + 4];
    float xv[8] = {xa.x, xa.y, xa.z, xa.w, xb.x, xb.y, xb.z, xb.w};
    float s = 0.f, s2 = 0.f;
#pragma unroll
    for (int i = 0; i < 8; ++i) { s += xv[i]; s2 += xv[i] * xv[i]; }
    s = wave_sum(s); s2 = wave_sum(s2);
    __shared__ float r1[4], r2[4];
    int w = threadIdx.x >> 6;
    if ((threadIdx.x & 63) == 0) { r1[w] = s; r2[w] = s2; }
    __syncthreads();
    float ts  = r1[0] + r1[1] + r1[2] + r1[3];
    float ts2 = r2[0] + r2[1] + r2[2] + r2[3];
    float mean = ts * (1.f / D_);
    float var  = ts2 * (1.f / D_) - mean * mean;
    float inv  = rsqrtf(var + EPS_);
    float4 wa0 = *(const float4*)&aw[base], wa1 = *(const float4*)&aw[base + 4];
    float4 ba0 = *(const float4*)&ab[base], ba1 = *(const float4*)&ab[base + 4];
    float4 wf0 = *(const float4*)&fw[base], wf1 = *(const float4*)&fw[base + 4];
    float4 bf0 = *(const float4*)&fb[base], bf1 = *(const float4*)&fb[base + 4];
    float wav[8] = {wa0.x, wa0.y, wa0.z, wa0.w, wa1.x, wa1.y, wa1.z, wa1.w};
    float bav[8] = {ba0.x, ba0.y, ba0.z, ba0.w, ba1.x, ba1.y, ba1.z, ba1.w};
    float wfv[8] = {wf0.x, wf0.y, wf0.z, wf0.w, wf1.x, wf1.y, wf1.z, wf1.w};
    float bfv[8] = {bf0.x, bf0.y, bf0.z, bf0.w, bf1.x, bf1.y, bf1.z, bf1.w};
    union { uint4 v; u16 s[8]; } o1, o2;
#pragma unroll
    for (int i = 0; i < 8; ++i) {
        float t = (xv[i] - mean) * inv;
        o1.s[i] = f2b(t * wav[i] + bav[i]);
        o2.s[i] = f2b(t * wfv[i] + bfv[i]);
    }
    *(uint4*)&nx[(size_t)row * D_ + base] = o1.v;
    *(uint4*)&f [(size_t)row * D_ + base] = o2.v;
}

// ---------------- MFMA GEMM: 128^2 tile, BK=64, swizzled LDS ---------------
// m97 2-phase structure with BK=64 + XOR LDS swizzle (QKV 99-102us @ ~48%
// MfmaUtil, conflicts 0).
// SWZ=0: plain 2D grid.  SWZ=1: WO/W2 map (grid 512, 8 XCD supertiles of
// 8x8 tiles).  SWZ=2: FFN1 map (grid 1024, 8 XCDs as 2x4 bands of 16x8).
// EPI 0: bf16 out.  EPI 1: fp32 out, += fp32 residual.  EPI 2: bf16, GELU.
template <int EPI, int SWZ>
__global__ __launch_bounds__(256, 2) void gemm_bt(
        const u16* __restrict__ A, const u16* __restrict__ BT,
        const float* __restrict__ bias, const float* __restrict__ res,
        void* __restrict__ Cv, int M, int N, int K) {
    __shared__ __align__(16) u16 As[128][64];
    __shared__ __align__(16) u16 Bs[128][64];
    int m0, n0;
    if (SWZ == 0) {
        m0 = blockIdx.y * 128; n0 = blockIdx.x * 128;
    } else if (SWZ == 1) {
        // grid = 512: XCD xc owns the 8x8-tile supertile (xc>>1, xc&1)
        int bid = blockIdx.x;
        int xc = bid & 7, ii = bid >> 3;
        int by = (xc >> 1) * 8 + (ii >> 3);
        int bx = (xc & 1) * 8 + (ii & 7);
        m0 = by * 128; n0 = bx * 128;
    } else {
        // grid = 1024 (32x32 tiles): XCD xc owns a 16x8-tile region
        int bid = blockIdx.x;
        int xc = bid & 7, ii = bid >> 3;          // ii 0..127
        int by = (xc >> 2) * 16 + (ii >> 3);      // 2 row-bands of 16
        int bx = (xc & 3) * 8 + (ii & 7);         // 4 col-bands of 8
        m0 = by * 128; n0 = bx * 128;
    }
    int w = threadIdx.x >> 6, lane = threadIdx.x & 63;
    int wm = (w >> 1) * 64, wn = (w & 1) * 64;
    int row16 = lane & 15, quad = lane >> 4;
    int lr  = lane >> 3;                  // staging row-within-8 (0..7)
    int lcs = ((lane & 7) ^ lr) << 3;     // pre-swizzled source col (u16)
    int xr  = (lane & 7) << 3;            // read-side col XOR (row16&7 == lane&7)
    f32x4 acc[4][4] = {};
    for (int k0 = 0; k0 < K; k0 += 64) {
        __syncthreads();
        // wave w stages rows [w*32, w*32+32) of both 128x64 tiles (8 DMAs)
#pragma unroll
        for (int j = 0; j < 4; ++j) {
            int rb = w * 32 + j * 8;
            gld_lds16(&A [(size_t)(m0 + rb + lr) * K + k0 + lcs], &As[rb][0]);
            gld_lds16(&BT[(size_t)(n0 + rb + lr) * K + k0 + lcs], &Bs[rb][0]);
        }
        __syncthreads();
        bf16x8 af[4][2], bfr[4][2];
#pragma unroll
        for (int i = 0; i < 4; ++i)
#pragma unroll
            for (int ks = 0; ks < 2; ++ks) {
                af[i][ks]  = *(const bf16x8*)&As[wm + i * 16 + row16][(ks * 32 + quad * 8) ^ xr];
                bfr[i][ks] = *(const bf16x8*)&Bs[wn + i * 16 + row16][(ks * 32 + quad * 8) ^ xr];
            }
#pragma unroll
        for (int mi = 0; mi < 4; ++mi)
#pragma unroll
            for (int ni = 0; ni < 4; ++ni)
#pragma unroll
                for (int ks = 0; ks < 2; ++ks)
                    acc[mi][ni] = __builtin_amdgcn_mfma_f32_16x16x32_bf16(
                            af[mi][ks], bfr[ni][ks], acc[mi][ni], 0, 0, 0);
    }
#pragma unroll
    for (int mi = 0; mi < 4; ++mi) {
#pragma unroll
        for (int ni = 0; ni < 4; ++ni) {
            int gcol = n0 + wn + ni * 16 + row16;
            float bv = bias[gcol];
#pragma unroll
            for (int i = 0; i < 4; ++i) {
                int grow = m0 + wm + mi * 16 + quad * 4 + i;
                float vv = acc[mi][ni][i] + bv;
                if (EPI == 1) {
                    vv += res[(size_t)grow * N + gcol];
                    ((float*)Cv)[(size_t)grow * N + gcol] = vv;
                } else {
                    if (EPI == 2)
                        vv = vv * 0.5f * (1.0f + erff(vv * 0.70710678118654752f));
                    ((u16*)Cv)[(size_t)grow * N + gcol] = f2b(vv);
                }
            }
        }
    }
}

// ---------------- QK RMSNorm + partial RoPE (q,k only), u32-vectorized -----
// One wave per (b,s,h). Lane l holds dims (2l, 2l+1) as one u32.
// RoPE: out[2j]=x0[j]c-x1[j]s, out[2j+1]=x1[j]c+x0[j]s, x0[j]=dim j,
// x1[j]=dim 16+j  -> lanes 0..15 produce their pair via 4 shuffles.
__global__ __launch_bounds__(256) void qk_rope(const u32* __restrict__ qkv32,
        const float* __restrict__ qn_w, const float* __restrict__ kn_w,
        const float* __restrict__ freqs,
        u32* __restrict__ q32, u32* __restrict__ k32) {
    int w = threadIdx.x >> 6, lane = threadIdx.x & 63;
    int unit = blockIdx.x * 4 + w;           // b*S*H + s*H + h
    int h = unit & (H_ - 1);
    int s = (unit >> 4) & (S_ - 1);
    int b = unit >> 15;
    size_t inbase  = (size_t)(b * S_ + s) * (3 * D_ / 2) + h * (HD_ / 2);
    size_t outbase = ((size_t)((b * H_ + h) * S_) + s) * (HD_ / 2);
    float fc = 0.f, fs = 0.f;
    if (lane < 16) {
        fc = freqs[(s * 16 + lane) * 2];
        fs = freqs[(s * 16 + lane) * 2 + 1];
    }
#pragma unroll
    for (int part = 0; part < 2; ++part) {   // 0: q, 1: k
        const float* nw = part ? kn_w : qn_w;
        u32 wv = qkv32[inbase + part * (D_ / 2) + lane];
        float a0 = b2f((u16)(wv & 0xffffu));
        float a1 = b2f((u16)(wv >> 16));
        float ss = wave_sum(a0 * a0 + a1 * a1);
        float inv = rsqrtf(ss * (1.f / HD_) + EPS_);
        float2 nwp = *(const float2*)&nw[2 * lane];
        float n0 = a0 * inv * nwp.x;
        float n1 = a1 * inv * nwp.y;
        // gather x0[j]=dim j (lane j>>1, parity j&1), x1[j]=dim 16+j
        float e0 = __shfl(n0, lane >> 1), e1 = __shfl(n1, lane >> 1);
        float o0 = __shfl(n0, 8 + (lane >> 1)), o1 = __shfl(n1, 8 + (lane >> 1));
        float x0 = (lane & 1) ? e1 : e0;
        float x1 = (lane & 1) ? o1 : o0;
        float rv0 = x0 * fc - x1 * fs;
        float rv1 = x1 * fc + x0 * fs;
        float w0 = (lane < 16) ? rv0 : n0;
        float w1 = (lane < 16) ? rv1 : n1;
        u32* dst = part ? k32 : q32;
        dst[outbase + lane] = (u32)f2b(w0) | ((u32)f2b(w1) << 16);
    }
}

// -------- V transpose: qkv V-part [b][s][h][d] -> vt [b][h][d][s] ----------
__global__ __launch_bounds__(256) void v_transpose(const u32* __restrict__ qkv32,
                                                   u32* __restrict__ vt32) {
    __shared__ u32 tile[64][17];
    int bh = blockIdx.z; int b = bh >> 4, h = bh & 15;
    int s0 = blockIdx.x * 64, d0 = blockIdx.y * 32;
    int tid = threadIdx.x;
    int rr = tid >> 4, cc = tid & 15;          // rr 0..15, cc 0..15 (u32 cols)
#pragma unroll
    for (int i = 0; i < 4; ++i) {
        int s = s0 + rr + i * 16;
        tile[rr + i * 16][cc] =
            qkv32[(size_t)(b * S_ + s) * (3 * D_ / 2) + (2 * D_ + h * HD_ + d0) / 2 + cc];
    }
    __syncthreads();
    int dr = tid & 31, sc = tid >> 5;          // dr 0..31, sc 0..7
#pragma unroll
    for (int i = 0; i < 4; ++i) {
        int s2 = sc + i * 8;                   // s-pair index 0..31
        u32 w0 = tile[2 * s2][dr >> 1];
        u32 w1 = tile[2 * s2 + 1][dr >> 1];
        u32 h0 = (dr & 1) ? (w0 >> 16) : (w0 & 0xffffu);
        u32 h1 = (dr & 1) ? (w1 >> 16) : (w1 & 0xffffu);
        vt32[((size_t)bh * HD_ + d0 + dr) * (S_ / 2) + (s0 >> 1) + s2] = h0 | (h1 << 16);
    }
}

// ---------------- MFMA sliding-window causal flash attention ---------------
// R18: QBLK=128, 8 waves (512 threads).  Wave w owns q-rows [qbase+16w,+16).
// Staging events per unit work halved vs QBLK=64; grid 512 = exactly 2/CU.
// Direct global->LDS staging (no cross-barrier registers - spill-proof).
__global__ __launch_bounds__(512) void attn_mfma(
        const u16* __restrict__ q, const u16* __restrict__ k,
        const u16* __restrict__ vt, u16* __restrict__ y) {
    __shared__ __align__(16) u16 Ks [64][136];   // 272B rows: 68-word stride
    __shared__ __align__(16) u16 Vts[128][72];   // 144B rows: 36-word stride
    __shared__ __align__(16) u16 Ps [8][16][72];
    int g2 = blockIdx.x & (S_ / 128 - 1);  // 0..15
    int bh = blockIdx.x >> 4;              // 0..31
    int qbase = g2 * 128;
    size_t kvbase = (size_t)bh * S_ * HD_;
    size_t vtbase = (size_t)bh * HD_ * S_;
    int w = threadIdx.x >> 6, lane = threadIdx.x & 63;   // w 0..7
    int col16 = lane & 15, quad = lane >> 4;
    int q0w = qbase + w * 16;
    bf16x8 af[4];
#pragma unroll
    for (int kb = 0; kb < 4; ++kb)
        af[kb] = *(const bf16x8*)&q[kvbase + (size_t)(q0w + col16) * HD_ + kb * 32 + quad * 8];
    f32x4 oacc[8] = {};
    float mrow[4], lrow[4];
#pragma unroll
    for (int i = 0; i < 4; ++i) { mrow[i] = -1e38f; lrow[i] = 0.f; }
    int t0 = 2 * g2 - 4; if (t0 < 0) t0 = 0;
    int tend = 2 * g2 + 1;
    int tid = threadIdx.x;
    int kr = tid >> 3, kc = (tid & 7) * 16;   // 64 rows x 128 u16, 16 u16/thread
    int vr = tid >> 2, vc = (tid & 3) * 16;   // 128 rows x 64 u16, 16 u16/thread
    for (int t = t0; t <= tend; ++t) {
        __syncthreads();
        {
            const u16* kg = &k[kvbase + (size_t)(t * 64 + kr) * HD_ + kc];
            *(uint4*)&Ks[kr][kc]     = *(const uint4*)&kg[0];
            *(uint4*)&Ks[kr][kc + 8] = *(const uint4*)&kg[8];
            const u16* vg = &vt[vtbase + (size_t)vr * S_ + t * 64 + vc];
            *(uint4*)&Vts[vr][vc]     = *(const uint4*)&vg[0];
            *(uint4*)&Vts[vr][vc + 8] = *(const uint4*)&vg[8];
        }
        __syncthreads();
        f32x4 sacc[4] = {};
#pragma unroll
        for (int ks = 0; ks < 4; ++ks)
#pragma unroll
            for (int kb = 0; kb < 4; ++kb) {
                bf16x8 bf = *(const bf16x8*)&Ks[ks * 16 + col16][kb * 32 + quad * 8];
                sacc[ks] = __builtin_amdgcn_mfma_f32_16x16x32_bf16(af[kb], bf, sacc[ks], 0, 0, 0);
            }
        float pm[4][4];
        float tmax[4] = {-3e38f, -3e38f, -3e38f, -3e38f};
#pragma unroll
        for (int ks = 0; ks < 4; ++ks) {
            int jg = t * 64 + ks * 16 + col16;
#pragma unroll
            for (int i = 0; i < 4; ++i) {
                int qi = q0w + quad * 4 + i;
                bool valid = (jg <= qi) && (qi - jg < WIN_);
                float sv = valid ? sacc[ks][i] * SCALE_ : -3e38f;
                pm[ks][i] = sv;
                tmax[i] = fmaxf(tmax[i], sv);
            }
        }
#pragma unroll
        for (int off = 8; off >= 1; off >>= 1)
#pragma unroll
            for (int i = 0; i < 4; ++i)
                tmax[i] = fmaxf(tmax[i], __shfl_xor(tmax[i], off));
        float alpha[4], psum[4];
#pragma unroll
        for (int i = 0; i < 4; ++i) {
            float mnew = fmaxf(mrow[i], tmax[i]);
            alpha[i] = __expf(mrow[i] - mnew);
            mrow[i] = mnew;
            psum[i] = 0.f;
        }
#pragma unroll
        for (int ks = 0; ks < 4; ++ks)
#pragma unroll
            for (int i = 0; i < 4; ++i) {
                float p = __expf(pm[ks][i] - mrow[i]);
                psum[i] += p;
                Ps[w][quad * 4 + i][ks * 16 + col16] = f2b(p);
            }
#pragma unroll
        for (int off = 8; off >= 1; off >>= 1)
#pragma unroll
            for (int i = 0; i < 4; ++i)
                psum[i] += __shfl_xor(psum[i], off);
#pragma unroll
        for (int i = 0; i < 4; ++i)
            lrow[i] = lrow[i] * alpha[i] + psum[i];
#pragma unroll
        for (int ns = 0; ns < 8; ++ns)
#pragma unroll
            for (int i = 0; i < 4; ++i)
                oacc[ns][i] *= alpha[i];
#pragma unroll
        for (int c = 0; c < 2; ++c) {
            bf16x8 pf = *(const bf16x8*)&Ps[w][col16][c * 32 + quad * 8];
#pragma unroll
            for (int ns = 0; ns < 8; ++ns) {
                bf16x8 vf = *(const bf16x8*)&Vts[ns * 16 + col16][c * 32 + quad * 8];
                oacc[ns] = __builtin_amdgcn_mfma_f32_16x16x32_bf16(pf, vf, oacc[ns], 0, 0, 0);
            }
        }
    }
    int b = bh >> 4, hh = bh & 15;
#pragma unroll
    for (int i = 0; i < 4; ++i) {
        int qi = q0w + quad * 4 + i;
        float invl = 1.f / lrow[i];
        size_t ob = (size_t)(b * S_ + qi) * D_ + hh * HD_;
#pragma unroll
        for (int ns = 0; ns < 8; ++ns)
            y[ob + ns * 16 + col16] = f2b(oacc[ns][i] * invl);
    }
}

// ---------------------------- host orchestration ---------------------------
extern "C" void kernel_launch(void* const* d_in, const int* in_sizes, int n_in,
                              void* d_out, int out_size, void* d_ws, size_t ws_size,
                              hipStream_t stream) {
    const float* x      = (const float*)d_in[0];
    const float* freqs  = (const float*)d_in[1];
    // d_in[2] = mask (unused; computed analytically)
    const float* wqkv_w = (const float*)d_in[3];
    const float* wqkv_b = (const float*)d_in[4];
    const float* wo_w   = (const float*)d_in[5];
    const float* wo_b   = (const float*)d_in[6];
    const float* qn_w   = (const float*)d_in[7];
    const float* kn_w   = (const float*)d_in[8];
    const float* aln_w  = (const float*)d_in[9];
    const float* aln_b  = (const float*)d_in[10];
    const float* fln_w  = (const float*)d_in[11];
    const float* fln_b  = (const float*)d_in[12];
    const float* w1_w   = (const float*)d_in[13];
    const float* w1_b   = (const float*)d_in[14];
    const float* w2_w   = (const float*)d_in[15];
    const float* w2_b   = (const float*)d_in[16];
    float* out = (float*)d_out;

    char* ws = (char*)d_ws;
    size_t off = 0;
    auto alloc = [&](size_t bytes) { char* p = ws + off; off += (bytes + 255) & ~(size_t)255; return (u16*)p; };
    const size_t E = sizeof(u16);
    u16* wt_qkv = alloc((size_t)D_ * 3 * D_ * E);       // bf16 [6144,2048]
    u16* wt_wo  = alloc((size_t)D_ * D_ * E);           // bf16 [2048,2048]
    u16* wt_w1  = alloc((size_t)D_ * FF_ * E);          // bf16 [4096,2048]
    u16* wt_w2  = alloc((size_t)FF_ * D_ * E);          // bf16 [2048,4096]
    u16* nx     = alloc((size_t)B_ * S_ * D_ * E);      // bf16; reused as y
    u16* f      = alloc((size_t)B_ * S_ * D_ * E);      // bf16
    u16* qkv    = alloc((size_t)B_ * S_ * 3 * D_ * E);  // bf16; reused as tmid
    u16* qb     = alloc((size_t)B_ * S_ * D_ * E);      // bf16 [b][h][s][d]
    u16* kb     = alloc((size_t)B_ * S_ * D_ * E);      // bf16 [b][h][s][d]
    u16* vtb    = alloc((size_t)B_ * S_ * D_ * E);      // bf16 [b][h][d][s]
    u16* y    = nx;    // nx consumed by QKV GEMM before attention writes y
    u16* tmid = qkv;   // qkv consumed by qk_rope/v_transpose before FFN1
    float* h  = out;   // h lives in d_out

    if (off > ws_size) return;  // tripwire -> finite err signature

    const int M = B_ * S_;  // 4096

    transpose_k<<<dim3(3 * D_ / 64, D_ / 64), 256, 0, stream>>>(wqkv_w, wt_qkv, D_, 3 * D_);
    transpose_k<<<dim3(D_ / 64, D_ / 64),     256, 0, stream>>>(wo_w,   wt_wo,  D_, D_);
    transpose_k<<<dim3(FF_ / 64, D_ / 64),    256, 0, stream>>>(w1_w,   wt_w1,  D_, FF_);
    transpose_k<<<dim3(D_ / 64, FF_ / 64),    256, 0, stream>>>(w2_w,   wt_w2,  FF_, D_);

    ln_dual<<<M, 256, 0, stream>>>(x, aln_w, aln_b, fln_w, fln_b, nx, f);

    // QKV: proven R13 2D-grid path
    gemm_bt<0, 0><<<dim3(3 * D_ / 128, M / 128), 256, 0, stream>>>(
            nx, wt_qkv, wqkv_b, nullptr, qkv, M, 3 * D_, D_);

    qk_rope<<<B_ * S_ * H_ / 4, 256, 0, stream>>>((const u32*)qkv, qn_w, kn_w, freqs, (u32*)qb, (u32*)kb);
    v_transpose<<<dim3(S_ / 64, HD_ / 32, B_ * H_), 256, 0, stream>>>((const u32*)qkv, (u32*)vtb);

    // QBLK=128: 512 blocks x 512 threads
    attn_mfma<<<B_ * H_ * (S_ / 128), 512, 0, stream>>>(qb, kb, vtb, y);

    // FFN1: 16x8 XCD-supertile remap (grid 1024)
    gemm_bt<2, 2><<<(FF_ / 128) * (M / 128), 256, 0, stream>>>(
            f, wt_w1, w1_b, nullptr, tmid, M, FF_, D_);

    // WO/W2: 8x8 XCD-supertile remap (grid 512)
    gemm_bt<1, 1><<<(D_ / 128) * (M / 128), 256, 0, stream>>>(
            y, wt_wo, wo_b, x, h, M, D_, D_);

    gemm_bt<1, 1><<<(D_ / 128) * (M / 128), 256, 0, stream>>>(
            tmid, wt_w2, w2_b, h, out, M, D_, FF_);
}

// Round 13
// 627.812 us; speedup vs baseline: 1.0962x; 1.0101x over previous
//
#include <hip/hip_runtime.h>

// TransformerBlock on MI355X (gfx950). External dtype: FP32. Internals bf16.
//   transpose_k: W fp32 [R][C] -> bf16 [C][R]  (64x64 tiles, u32 stores)
//   ln_dual:     nx = LN(x,attn_ln), f = LN(x,ffn_ln)
//   gemm<0,0>:   qkv = nx @ Wqkv + b          (128^2, BK=64, swizzled LDS, 2D grid)
//   qk_rope:     RMSNorm + RoPE(first 32 dims) on q,k   (u32-vectorized)
//   v_transpose: V part of qkv -> vt [b][h][dim][key]
//   attn_mfma:   sliding-window(256) causal flash attention, MFMA,
//                LDS-double-buffered DMA staging (T3 minimum 2-phase)
//   gemm<2,2>:   tmid = gelu_exact(f @ W1 + b1)   (16x8 XCD supertile)
//   gemm<1,1>:   h = x + y @ Wo + b           (fp32, in d_out; 8x8 XCD supertile)
//   gemm<1,1>:   out = h + tmid @ W2 + b2     (8x8 XCD supertile)
//
// R18 -> R19: attention staging moved to global_load_lds DMA with LDS
// double-buffering (T3 minimum-2-phase).  Spill-proof: DMA uses no data
// registers (the R11/R16 failure mode cannot occur).  Per iter: barrier
// (drains prior DMA) -> issue DMA t+1 -> buf^1 -> compute buf -> barrier
// (drains t+1 DMA after the whole compute phase => ~free).  K/V tiles
// unpadded + the gemm_bt XOR swizzle (HW-verified conflict-free, same
// read pattern).  LDS 73KB -> 2 blocks/CU.  QBLK back to 64 (128 was
// neutral).  Everything else identical to R18 (634.2us best).

typedef unsigned short u16;
typedef unsigned int   u32;
typedef __bf16 bf16x8 __attribute__((ext_vector_type(8)));
typedef float  f32x4  __attribute__((ext_vector_type(4)));
typedef __attribute__((address_space(3))) u32 as3_u32;
typedef __attribute__((address_space(1))) u32 as1_u32;

#define B_    2
#define S_    2048
#define D_    2048
#define H_    16
#define HD_   128
#define FF_   4096
#define WIN_  256
#define EPS_  1e-5f
#define SCALE_ 0.08838834764831845f  // 1/sqrt(128)

__device__ __forceinline__ float b2f(u16 u) {
    return __uint_as_float(((u32)u) << 16);
}
__device__ __forceinline__ u16 f2b(float f) {
    u32 u = __float_as_uint(f);
    u32 r = (u + 0x7fffu + ((u >> 16) & 1u)) >> 16;  // RNE
    return (u16)r;
}
__device__ __forceinline__ float wave_sum(float v) {
#pragma unroll
    for (int o = 32; o > 0; o >>= 1) v += __shfl_xor(v, o);
    return v;
}
// async 16B/lane global->LDS; lds base must be wave-uniform, lane i lands at
// base + i*16 (m97 pattern).
__device__ __forceinline__ void gld_lds16(const u16* g, u16* l) {
    __builtin_amdgcn_global_load_lds((const as1_u32*)g, (as3_u32*)l, 16, 0, 0);
}

// -------- weight transpose + cast: in fp32 [R][C] -> out bf16 [C][R] -------
// 64x64 tile; write phase packs row-pairs into u32 (contiguous along R).
__global__ __launch_bounds__(256) void transpose_k(const float* __restrict__ in,
                                                   u16* __restrict__ out,
                                                   int R, int C) {
    __shared__ float tile[64][65];
    int t = threadIdx.x;
    int r0 = blockIdx.y * 64, c0 = blockIdx.x * 64;
    int rr = t >> 2;              // 0..63
    int cb = (t & 3) * 16;        // 0,16,32,48
    const float* src = &in[(size_t)(r0 + rr) * C + c0 + cb];
#pragma unroll
    for (int j = 0; j < 16; j += 4) {
        float4 v = *(const float4*)&src[j];
        tile[rr][cb + j]     = v.x; tile[rr][cb + j + 1] = v.y;
        tile[rr][cb + j + 2] = v.z; tile[rr][cb + j + 3] = v.w;
    }
    __syncthreads();
    int wq = t & 31;              // row-pair 0..31 (rows 2wq, 2wq+1)
    int ch = t >> 5;              // 0..7
#pragma unroll
    for (int i = 0; i < 8; ++i) {
        int c = ch * 8 + i;       // 0..63
        u32 lo = (u32)f2b(tile[2 * wq][c]);
        u32 hi = (u32)f2b(tile[2 * wq + 1][c]);
        ((u32*)out)[(((size_t)(c0 + c) * R) >> 1) + (r0 >> 1) + wq] = lo | (hi << 16);
    }
}

// ---------- dual LayerNorm: fp32 x -> bf16 nx, f (one pass) ----------------
__global__ __launch_bounds__(256) void ln_dual(const float* __restrict__ x,
        const float* __restrict__ aw, const float* __restrict__ ab,
        const float* __restrict__ fw, const float* __restrict__ fb,
        u16* __restrict__ nx, u16* __restrict__ f) {
    int row = blockIdx.x;                // 0..B*S-1
    const float* xr = x + (size_t)row * D_;
    int base = threadIdx.x * 8;
    float4 xa = *(const float4*)&xr[base];
    float4 xb = *(const float4*)&xr[base + 4];
    float xv[8] = {xa.x, xa.y, xa.z, xa.w, xb.x, xb.y, xb.z, xb.w};
    float s = 0.f, s2 = 0.f;
#pragma unroll
    for (int i = 0; i < 8; ++i) { s += xv[i]; s2 += xv[i] * xv[i]; }
    s = wave_sum(s); s2 = wave_sum(s2);
    __shared__ float r1[4], r2[4];
    int w = threadIdx.x >> 6;
    if ((threadIdx.x & 63) == 0) { r1[w] = s; r2[w] = s2; }
    __syncthreads();
    float ts  = r1[0] + r1[1] + r1[2] + r1[3];
    float ts2 = r2[0] + r2[1] + r2[2] + r2[3];
    float mean = ts * (1.f / D_);
    float var  = ts2 * (1.f / D_) - mean * mean;
    float inv  = rsqrtf(var + EPS_);
    float4 wa0 = *(const float4*)&aw[base], wa1 = *(const float4*)&aw[base + 4];
    float4 ba0 = *(const float4*)&ab[base], ba1 = *(const float4*)&ab[base + 4];
    float4 wf0 = *(const float4*)&fw[base], wf1 = *(const float4*)&fw[base + 4];
    float4 bf0 = *(const float4*)&fb[base], bf1 = *(const float4*)&fb[base + 4];
    float wav[8] = {wa0.x, wa0.y, wa0.z, wa0.w, wa1.x, wa1.y, wa1.z, wa1.w};
    float bav[8] = {ba0.x, ba0.y, ba0.z, ba0.w, ba1.x, ba1.y, ba1.z, ba1.w};
    float wfv[8] = {wf0.x, wf0.y, wf0.z, wf0.w, wf1.x, wf1.y, wf1.z, wf1.w};
    float bfv[8] = {bf0.x, bf0.y, bf0.z, bf0.w, bf1.x, bf1.y, bf1.z, bf1.w};
    union { uint4 v; u16 s[8]; } o1, o2;
#pragma unroll
    for (int i = 0; i < 8; ++i) {
        float t = (xv[i] - mean) * inv;
        o1.s[i] = f2b(t * wav[i] + bav[i]);
        o2.s[i] = f2b(t * wfv[i] + bfv[i]);
    }
    *(uint4*)&nx[(size_t)row * D_ + base] = o1.v;
    *(uint4*)&f [(size_t)row * D_ + base] = o2.v;
}

// ---------------- MFMA GEMM: 128^2 tile, BK=64, swizzled LDS ---------------
// m97 2-phase structure with BK=64 + XOR LDS swizzle (QKV 99-102us @ ~48%
// MfmaUtil, conflicts 0).
// SWZ=0: plain 2D grid.  SWZ=1: WO/W2 map (grid 512, 8 XCD supertiles of
// 8x8 tiles).  SWZ=2: FFN1 map (grid 1024, 8 XCDs as 2x4 bands of 16x8).
// EPI 0: bf16 out.  EPI 1: fp32 out, += fp32 residual.  EPI 2: bf16, GELU.
template <int EPI, int SWZ>
__global__ __launch_bounds__(256, 2) void gemm_bt(
        const u16* __restrict__ A, const u16* __restrict__ BT,
        const float* __restrict__ bias, const float* __restrict__ res,
        void* __restrict__ Cv, int M, int N, int K) {
    __shared__ __align__(16) u16 As[128][64];
    __shared__ __align__(16) u16 Bs[128][64];
    int m0, n0;
    if (SWZ == 0) {
        m0 = blockIdx.y * 128; n0 = blockIdx.x * 128;
    } else if (SWZ == 1) {
        // grid = 512: XCD xc owns the 8x8-tile supertile (xc>>1, xc&1)
        int bid = blockIdx.x;
        int xc = bid & 7, ii = bid >> 3;
        int by = (xc >> 1) * 8 + (ii >> 3);
        int bx = (xc & 1) * 8 + (ii & 7);
        m0 = by * 128; n0 = bx * 128;
    } else {
        // grid = 1024 (32x32 tiles): XCD xc owns a 16x8-tile region
        int bid = blockIdx.x;
        int xc = bid & 7, ii = bid >> 3;          // ii 0..127
        int by = (xc >> 2) * 16 + (ii >> 3);      // 2 row-bands of 16
        int bx = (xc & 3) * 8 + (ii & 7);         // 4 col-bands of 8
        m0 = by * 128; n0 = bx * 128;
    }
    int w = threadIdx.x >> 6, lane = threadIdx.x & 63;
    int wm = (w >> 1) * 64, wn = (w & 1) * 64;
    int row16 = lane & 15, quad = lane >> 4;
    int lr  = lane >> 3;                  // staging row-within-8 (0..7)
    int lcs = ((lane & 7) ^ lr) << 3;     // pre-swizzled source col (u16)
    int xr  = (lane & 7) << 3;            // read-side col XOR (row16&7 == lane&7)
    f32x4 acc[4][4] = {};
    for (int k0 = 0; k0 < K; k0 += 64) {
        __syncthreads();
        // wave w stages rows [w*32, w*32+32) of both 128x64 tiles (8 DMAs)
#pragma unroll
        for (int j = 0; j < 4; ++j) {
            int rb = w * 32 + j * 8;
            gld_lds16(&A [(size_t)(m0 + rb + lr) * K + k0 + lcs], &As[rb][0]);
            gld_lds16(&BT[(size_t)(n0 + rb + lr) * K + k0 + lcs], &Bs[rb][0]);
        }
        __syncthreads();
        bf16x8 af[4][2], bfr[4][2];
#pragma unroll
        for (int i = 0; i < 4; ++i)
#pragma unroll
            for (int ks = 0; ks < 2; ++ks) {
                af[i][ks]  = *(const bf16x8*)&As[wm + i * 16 + row16][(ks * 32 + quad * 8) ^ xr];
                bfr[i][ks] = *(const bf16x8*)&Bs[wn + i * 16 + row16][(ks * 32 + quad * 8) ^ xr];
            }
#pragma unroll
        for (int mi = 0; mi < 4; ++mi)
#pragma unroll
            for (int ni = 0; ni < 4; ++ni)
#pragma unroll
                for (int ks = 0; ks < 2; ++ks)
                    acc[mi][ni] = __builtin_amdgcn_mfma_f32_16x16x32_bf16(
                            af[mi][ks], bfr[ni][ks], acc[mi][ni], 0, 0, 0);
    }
#pragma unroll
    for (int mi = 0; mi < 4; ++mi) {
#pragma unroll
        for (int ni = 0; ni < 4; ++ni) {
            int gcol = n0 + wn + ni * 16 + row16;
            float bv = bias[gcol];
#pragma unroll
            for (int i = 0; i < 4; ++i) {
                int grow = m0 + wm + mi * 16 + quad * 4 + i;
                float vv = acc[mi][ni][i] + bv;
                if (EPI == 1) {
                    vv += res[(size_t)grow * N + gcol];
                    ((float*)Cv)[(size_t)grow * N + gcol] = vv;
                } else {
                    if (EPI == 2)
                        vv = vv * 0.5f * (1.0f + erff(vv * 0.70710678118654752f));
                    ((u16*)Cv)[(size_t)grow * N + gcol] = f2b(vv);
                }
            }
        }
    }
}

// ---------------- QK RMSNorm + partial RoPE (q,k only), u32-vectorized -----
// One wave per (b,s,h). Lane l holds dims (2l, 2l+1) as one u32.
// RoPE: out[2j]=x0[j]c-x1[j]s, out[2j+1]=x1[j]c+x0[j]s, x0[j]=dim j,
// x1[j]=dim 16+j  -> lanes 0..15 produce their pair via 4 shuffles.
__global__ __launch_bounds__(256) void qk_rope(const u32* __restrict__ qkv32,
        const float* __restrict__ qn_w, const float* __restrict__ kn_w,
        const float* __restrict__ freqs,
        u32* __restrict__ q32, u32* __restrict__ k32) {
    int w = threadIdx.x >> 6, lane = threadIdx.x & 63;
    int unit = blockIdx.x * 4 + w;           // b*S*H + s*H + h
    int h = unit & (H_ - 1);
    int s = (unit >> 4) & (S_ - 1);
    int b = unit >> 15;
    size_t inbase  = (size_t)(b * S_ + s) * (3 * D_ / 2) + h * (HD_ / 2);
    size_t outbase = ((size_t)((b * H_ + h) * S_) + s) * (HD_ / 2);
    float fc = 0.f, fs = 0.f;
    if (lane < 16) {
        fc = freqs[(s * 16 + lane) * 2];
        fs = freqs[(s * 16 + lane) * 2 + 1];
    }
#pragma unroll
    for (int part = 0; part < 2; ++part) {   // 0: q, 1: k
        const float* nw = part ? kn_w : qn_w;
        u32 wv = qkv32[inbase + part * (D_ / 2) + lane];
        float a0 = b2f((u16)(wv & 0xffffu));
        float a1 = b2f((u16)(wv >> 16));
        float ss = wave_sum(a0 * a0 + a1 * a1);
        float inv = rsqrtf(ss * (1.f / HD_) + EPS_);
        float2 nwp = *(const float2*)&nw[2 * lane];
        float n0 = a0 * inv * nwp.x;
        float n1 = a1 * inv * nwp.y;
        // gather x0[j]=dim j (lane j>>1, parity j&1), x1[j]=dim 16+j
        float e0 = __shfl(n0, lane >> 1), e1 = __shfl(n1, lane >> 1);
        float o0 = __shfl(n0, 8 + (lane >> 1)), o1 = __shfl(n1, 8 + (lane >> 1));
        float x0 = (lane & 1) ? e1 : e0;
        float x1 = (lane & 1) ? o1 : o0;
        float rv0 = x0 * fc - x1 * fs;
        float rv1 = x1 * fc + x0 * fs;
        float w0 = (lane < 16) ? rv0 : n0;
        float w1 = (lane < 16) ? rv1 : n1;
        u32* dst = part ? k32 : q32;
        dst[outbase + lane] = (u32)f2b(w0) | ((u32)f2b(w1) << 16);
    }
}

// -------- V transpose: qkv V-part [b][s][h][d] -> vt [b][h][d][s] ----------
__global__ __launch_bounds__(256) void v_transpose(const u32* __restrict__ qkv32,
                                                   u32* __restrict__ vt32) {
    __shared__ u32 tile[64][17];
    int bh = blockIdx.z; int b = bh >> 4, h = bh & 15;
    int s0 = blockIdx.x * 64, d0 = blockIdx.y * 32;
    int tid = threadIdx.x;
    int rr = tid >> 4, cc = tid & 15;          // rr 0..15, cc 0..15 (u32 cols)
#pragma unroll
    for (int i = 0; i < 4; ++i) {
        int s = s0 + rr + i * 16;
        tile[rr + i * 16][cc] =
            qkv32[(size_t)(b * S_ + s) * (3 * D_ / 2) + (2 * D_ + h * HD_ + d0) / 2 + cc];
    }
    __syncthreads();
    int dr = tid & 31, sc = tid >> 5;          // dr 0..31, sc 0..7
#pragma unroll
    for (int i = 0; i < 4; ++i) {
        int s2 = sc + i * 8;                   // s-pair index 0..31
        u32 w0 = tile[2 * s2][dr >> 1];
        u32 w1 = tile[2 * s2 + 1][dr >> 1];
        u32 h0 = (dr & 1) ? (w0 >> 16) : (w0 & 0xffffu);
        u32 h1 = (dr & 1) ? (w1 >> 16) : (w1 & 0xffffu);
        vt32[((size_t)bh * HD_ + d0 + dr) * (S_ / 2) + (s0 >> 1) + s2] = h0 | (h1 << 16);
    }
}

// ---------------- MFMA sliding-window causal flash attention ---------------
// R19: LDS double-buffered DMA staging (T3 minimum 2-phase, spill-proof).
// Unpadded K/V tiles + gemm_bt XOR swizzle (conflict-free).  Per iter:
// barrier (prior DMA drained) -> DMA t+1 -> buf^1 -> compute buf -> barrier
// (t+1 DMA had whole compute to land => ~free drain).
__global__ __launch_bounds__(256) void attn_mfma(
        const u16* __restrict__ q, const u16* __restrict__ k,
        const u16* __restrict__ vt, u16* __restrict__ y) {
    __shared__ __align__(16) u16 Ks [2][64][128];   // 32KB, unpadded (DMA dest)
    __shared__ __align__(16) u16 Vts[2][128][64];   // 32KB, unpadded (DMA dest)
    __shared__ __align__(16) u16 Ps [4][16][72];    // 9KB (per-wave, intra-wave use)
    int g  = blockIdx.x & (S_ / 64 - 1);   // 0..31
    int bh = blockIdx.x >> 5;              // 0..31
    int qbase = g * 64;
    size_t kvbase = (size_t)bh * S_ * HD_;
    size_t vtbase = (size_t)bh * HD_ * S_;
    int w = threadIdx.x >> 6, lane = threadIdx.x & 63;
    int col16 = lane & 15, quad = lane >> 4;
    int xr = (lane & 7) << 3;              // read col XOR ((row&7)<<3, row=*16+col16)
    int q0w = qbase + w * 16;
    bf16x8 af[4];
#pragma unroll
    for (int kb = 0; kb < 4; ++kb)
        af[kb] = *(const bf16x8*)&q[kvbase + (size_t)(q0w + col16) * HD_ + kb * 32 + quad * 8];
    f32x4 oacc[8] = {};
    float mrow[4], lrow[4];
#pragma unroll
    for (int i = 0; i < 4; ++i) { mrow[i] = -1e38f; lrow[i] = 0.f; }
    int t0 = g >= 4 ? g - 4 : 0;

    // DMA staging: K tile 16 DMAs (4 rows each), V tile 16 DMAs (8 rows each);
    // wave w issues 4+4.  Source col-slot pre-swizzled with (row&7) so that
    // read col ^ ((row&7)<<3) recovers linear data (gemm_bt pattern).
    auto stageK = [&](int buf, int t) {
#pragma unroll
        for (int j = 0; j < 4; ++j) {
            int rb  = w * 16 + j * 4;
            int row = rb + (lane >> 4);
            int ss  = (lane & 15) ^ (row & 7);
            gld_lds16(&k[kvbase + (size_t)(t * 64 + row) * HD_ + ss * 8],
                      &Ks[buf][rb][0]);
        }
    };
    auto stageV = [&](int buf, int t) {
#pragma unroll
        for (int j = 0; j < 4; ++j) {
            int rb  = w * 32 + j * 8;
            int row = rb + (lane >> 3);
            int ss  = (lane & 7) ^ (lane >> 3);
            gld_lds16(&vt[vtbase + (size_t)row * S_ + t * 64 + ss * 8],
                      &Vts[buf][rb][0]);
        }
    };

    stageK(0, t0); stageV(0, t0);   // prologue
    int cur = 0;
    for (int t = t0; t <= g; ++t) {
        __syncthreads();            // drains outstanding DMA: buf[cur] ready
        if (t < g) { stageK(cur ^ 1, t + 1); stageV(cur ^ 1, t + 1); }
        f32x4 sacc[4] = {};
#pragma unroll
        for (int ks = 0; ks < 4; ++ks)
#pragma unroll
            for (int kb = 0; kb < 4; ++kb) {
                bf16x8 bf = *(const bf16x8*)&Ks[cur][ks * 16 + col16][(kb * 32 + quad * 8) ^ xr];
                sacc[ks] = __builtin_amdgcn_mfma_f32_16x16x32_bf16(af[kb], bf, sacc[ks], 0, 0, 0);
            }
        float pm[4][4];
        float tmax[4] = {-3e38f, -3e38f, -3e38f, -3e38f};
#pragma unroll
        for (int ks = 0; ks < 4; ++ks) {
            int jg = t * 64 + ks * 16 + col16;
#pragma unroll
            for (int i = 0; i < 4; ++i) {
                int qi = q0w + quad * 4 + i;
                bool valid = (jg <= qi) && (qi - jg < WIN_);
                float sv = valid ? sacc[ks][i] * SCALE_ : -3e38f;
                pm[ks][i] = sv;
                tmax[i] = fmaxf(tmax[i], sv);
            }
        }
#pragma unroll
        for (int off = 8; off >= 1; off >>= 1)
#pragma unroll
            for (int i = 0; i < 4; ++i)
                tmax[i] = fmaxf(tmax[i], __shfl_xor(tmax[i], off));
        float alpha[4], psum[4];
#pragma unroll
        for (int i = 0; i < 4; ++i) {
            float mnew = fmaxf(mrow[i], tmax[i]);
            alpha[i] = __expf(mrow[i] - mnew);
            mrow[i] = mnew;
            psum[i] = 0.f;
        }
#pragma unroll
        for (int ks = 0; ks < 4; ++ks)
#pragma unroll
            for (int i = 0; i < 4; ++i) {
                float p = __expf(pm[ks][i] - mrow[i]);
                psum[i] += p;
                Ps[w][quad * 4 + i][ks * 16 + col16] = f2b(p);
            }
#pragma unroll
        for (int off = 8; off >= 1; off >>= 1)
#pragma unroll
            for (int i = 0; i < 4; ++i)
                psum[i] += __shfl_xor(psum[i], off);
#pragma unroll
        for (int i = 0; i < 4; ++i)
            lrow[i] = lrow[i] * alpha[i] + psum[i];
#pragma unroll
        for (int ns = 0; ns < 8; ++ns)
#pragma unroll
            for (int i = 0; i < 4; ++i)
                oacc[ns][i] *= alpha[i];
#pragma unroll
        for (int c = 0; c < 2; ++c) {
            bf16x8 pf = *(const bf16x8*)&Ps[w][col16][c * 32 + quad * 8];
#pragma unroll
            for (int ns = 0; ns < 8; ++ns) {
                bf16x8 vf = *(const bf16x8*)&Vts[cur][ns * 16 + col16][(c * 32 + quad * 8) ^ xr];
                oacc[ns] = __builtin_amdgcn_mfma_f32_16x16x32_bf16(pf, vf, oacc[ns], 0, 0, 0);
            }
        }
        __syncthreads();            // all reads of buf[cur] done; t+1 DMA drains (~free)
        cur ^= 1;
    }
    int b = bh >> 4, hh = bh & 15;
#pragma unroll
    for (int i = 0; i < 4; ++i) {
        int qi = q0w + quad * 4 + i;
        float invl = 1.f / lrow[i];
        size_t ob = (size_t)(b * S_ + qi) * D_ + hh * HD_;
#pragma unroll
        for (int ns = 0; ns < 8; ++ns)
            y[ob + ns * 16 + col16] = f2b(oacc[ns][i] * invl);
    }
}

// ---------------------------- host orchestration ---------------------------
extern "C" void kernel_launch(void* const* d_in, const int* in_sizes, int n_in,
                              void* d_out, int out_size, void* d_ws, size_t ws_size,
                              hipStream_t stream) {
    const float* x      = (const float*)d_in[0];
    const float* freqs  = (const float*)d_in[1];
    // d_in[2] = mask (unused; computed analytically)
    const float* wqkv_w = (const float*)d_in[3];
    const float* wqkv_b = (const float*)d_in[4];
    const float* wo_w   = (const float*)d_in[5];
    const float* wo_b   = (const float*)d_in[6];
    const float* qn_w   = (const float*)d_in[7];
    const float* kn_w   = (const float*)d_in[8];
    const float* aln_w  = (const float*)d_in[9];
    const float* aln_b  = (const float*)d_in[10];
    const float* fln_w  = (const float*)d_in[11];
    const float* fln_b  = (const float*)d_in[12];
    const float* w1_w   = (const float*)d_in[13];
    const float* w1_b   = (const float*)d_in[14];
    const float* w2_w   = (const float*)d_in[15];
    const float* w2_b   = (const float*)d_in[16];
    float* out = (float*)d_out;

    char* ws = (char*)d_ws;
    size_t off = 0;
    auto alloc = [&](size_t bytes) { char* p = ws + off; off += (bytes + 255) & ~(size_t)255; return (u16*)p; };
    const size_t E = sizeof(u16);
    u16* wt_qkv = alloc((size_t)D_ * 3 * D_ * E);       // bf16 [6144,2048]
    u16* wt_wo  = alloc((size_t)D_ * D_ * E);           // bf16 [2048,2048]
    u16* wt_w1  = alloc((size_t)D_ * FF_ * E);          // bf16 [4096,2048]
    u16* wt_w2  = alloc((size_t)FF_ * D_ * E);          // bf16 [2048,4096]
    u16* nx     = alloc((size_t)B_ * S_ * D_ * E);      // bf16; reused as y
    u16* f      = alloc((size_t)B_ * S_ * D_ * E);      // bf16
    u16* qkv    = alloc((size_t)B_ * S_ * 3 * D_ * E);  // bf16; reused as tmid
    u16* qb     = alloc((size_t)B_ * S_ * D_ * E);      // bf16 [b][h][s][d]
    u16* kb     = alloc((size_t)B_ * S_ * D_ * E);      // bf16 [b][h][s][d]
    u16* vtb    = alloc((size_t)B_ * S_ * D_ * E);      // bf16 [b][h][d][s]
    u16* y    = nx;    // nx consumed by QKV GEMM before attention writes y
    u16* tmid = qkv;   // qkv consumed by qk_rope/v_transpose before FFN1
    float* h  = out;   // h lives in d_out

    if (off > ws_size) return;  // tripwire -> finite err signature

    const int M = B_ * S_;  // 4096

    transpose_k<<<dim3(3 * D_ / 64, D_ / 64), 256, 0, stream>>>(wqkv_w, wt_qkv, D_, 3 * D_);
    transpose_k<<<dim3(D_ / 64, D_ / 64),     256, 0, stream>>>(wo_w,   wt_wo,  D_, D_);
    transpose_k<<<dim3(FF_ / 64, D_ / 64),    256, 0, stream>>>(w1_w,   wt_w1,  D_, FF_);
    transpose_k<<<dim3(D_ / 64, FF_ / 64),    256, 0, stream>>>(w2_w,   wt_w2,  FF_, D_);

    ln_dual<<<M, 256, 0, stream>>>(x, aln_w, aln_b, fln_w, fln_b, nx, f);

    // QKV: proven R13 2D-grid path
    gemm_bt<0, 0><<<dim3(3 * D_ / 128, M / 128), 256, 0, stream>>>(
            nx, wt_qkv, wqkv_b, nullptr, qkv, M, 3 * D_, D_);

    qk_rope<<<B_ * S_ * H_ / 4, 256, 0, stream>>>((const u32*)qkv, qn_w, kn_w, freqs, (u32*)qb, (u32*)kb);
    v_transpose<<<dim3(S_ / 64, HD_ / 32, B_ * H_), 256, 0, stream>>>((const u32*)qkv, (u32*)vtb);

    attn_mfma<<<B_ * H_ * (S_ / 64), 256, 0, stream>>>(qb, kb, vtb, y);

    // FFN1: 16x8 XCD-supertile remap (grid 1024)
    gemm_bt<2, 2><<<(FF_ / 128) * (M / 128), 256, 0, stream>>>(
            f, wt_w1, w1_b, nullptr, tmid, M, FF_, D_);

    // WO/W2: 8x8 XCD-supertile remap (grid 512)
    gemm_bt<1, 1><<<(D_ / 128) * (M / 128), 256, 0, stream>>>(
            y, wt_wo, wo_b, x, h, M, D_, D_);

    gemm_bt<1, 1><<<(D_ / 128) * (M / 128), 256, 0, stream>>>(
            tmid, wt_w2, w2_b, h, out, M, D_, FF_);
}

// Round 14
// 600.798 us; speedup vs baseline: 1.1455x; 1.0450x over previous
//
#include <hip/hip_runtime.h>

// TransformerBlock on MI355X (gfx950). External dtype: FP32. Internals bf16.
//   transpose_k4: all 4 weights fp32 [R][C] -> bf16 [C][R] in ONE launch
//   ln_dual:     nx = LN(x,attn_ln), f = LN(x,ffn_ln)
//   gemm<0,0>:   qkv = nx @ Wqkv + b          (128^2, BK=64, swizzled LDS, 2D grid)
//   qk_rope:     RMSNorm + RoPE(first 32 dims) on q,k   (u32-vectorized)
//   v_transpose: V part of qkv -> vt [b][h][dim][key]
//   attn_mfma:   sliding-window(256) causal flash attention, MFMA,
//                LDS-double-buffered DMA staging + bh-grouped XCD swizzle
//   gemm<2,2>:   tmid = gelu_exact(f @ W1 + b1)   (16x8 XCD supertile)
//   gemm<1,1>:   h = x + y @ Wo + b           (fp32, in d_out; 8x8 XCD supertile)
//   gemm<1,1>:   out = h + tmid @ W2 + b2     (8x8 XCD supertile)
//
// R19 -> R20 (627.8us best):
//  (1) attn XCD swizzle: default bid=bh*32+g round-robins same-bh blocks
//      across XCDs -> each XCD touches all 32 heads' K/V (32MB, L2 thrash;
//      ~5x tile reuse served from L3).  Remap bh=(bid&7)*4+(ii>>5), g=ii&31
//      -> resident per-XCD working set 2 heads (2MB) -> reuse hits L2.
//  (2) four transpose_k launches merged into one segmented kernel (saves
//      3 dispatch overheads + tails).  Bodies byte-identical otherwise.

typedef unsigned short u16;
typedef unsigned int   u32;
typedef __bf16 bf16x8 __attribute__((ext_vector_type(8)));
typedef float  f32x4  __attribute__((ext_vector_type(4)));
typedef __attribute__((address_space(3))) u32 as3_u32;
typedef __attribute__((address_space(1))) u32 as1_u32;

#define B_    2
#define S_    2048
#define D_    2048
#define H_    16
#define HD_   128
#define FF_   4096
#define WIN_  256
#define EPS_  1e-5f
#define SCALE_ 0.08838834764831845f  // 1/sqrt(128)

__device__ __forceinline__ float b2f(u16 u) {
    return __uint_as_float(((u32)u) << 16);
}
__device__ __forceinline__ u16 f2b(float f) {
    u32 u = __float_as_uint(f);
    u32 r = (u + 0x7fffu + ((u >> 16) & 1u)) >> 16;  // RNE
    return (u16)r;
}
__device__ __forceinline__ float wave_sum(float v) {
#pragma unroll
    for (int o = 32; o > 0; o >>= 1) v += __shfl_xor(v, o);
    return v;
}
// async 16B/lane global->LDS; lds base must be wave-uniform, lane i lands at
// base + i*16 (m97 pattern).
__device__ __forceinline__ void gld_lds16(const u16* g, u16* l) {
    __builtin_amdgcn_global_load_lds((const as1_u32*)g, (as3_u32*)l, 16, 0, 0);
}

// -------- weight transpose + cast: fp32 [R][C] -> bf16 [C][R], 4-in-1 ------
// 64x64 tile; write phase packs row-pairs into u32 (contiguous along R).
// Segments: wqkv 3072 blocks, wo 1024, w1 2048, w2 2048 (total 8192).
__global__ __launch_bounds__(256) void transpose_k4(
        const float* __restrict__ i0, u16* __restrict__ o0,
        const float* __restrict__ i1, u16* __restrict__ o1,
        const float* __restrict__ i2, u16* __restrict__ o2,
        const float* __restrict__ i3, u16* __restrict__ o3) {
    __shared__ float tile[64][65];
    int bid = blockIdx.x;
    const float* in; u16* out; int R, C, local;
    if (bid < 3072)      { in = i0; out = o0; R = D_;  C = 3 * D_; local = bid; }
    else if (bid < 4096) { in = i1; out = o1; R = D_;  C = D_;     local = bid - 3072; }
    else if (bid < 6144) { in = i2; out = o2; R = D_;  C = FF_;    local = bid - 4096; }
    else                 { in = i3; out = o3; R = FF_; C = D_;     local = bid - 6144; }
    int nbx = C >> 6;
    int r0 = (local / nbx) * 64, c0 = (local % nbx) * 64;
    int t = threadIdx.x;
    int rr = t >> 2;              // 0..63
    int cb = (t & 3) * 16;        // 0,16,32,48
    const float* src = &in[(size_t)(r0 + rr) * C + c0 + cb];
#pragma unroll
    for (int j = 0; j < 16; j += 4) {
        float4 v = *(const float4*)&src[j];
        tile[rr][cb + j]     = v.x; tile[rr][cb + j + 1] = v.y;
        tile[rr][cb + j + 2] = v.z; tile[rr][cb + j + 3] = v.w;
    }
    __syncthreads();
    int wq = t & 31;              // row-pair 0..31 (rows 2wq, 2wq+1)
    int ch = t >> 5;              // 0..7
#pragma unroll
    for (int i = 0; i < 8; ++i) {
        int c = ch * 8 + i;       // 0..63
        u32 lo = (u32)f2b(tile[2 * wq][c]);
        u32 hi = (u32)f2b(tile[2 * wq + 1][c]);
        ((u32*)out)[(((size_t)(c0 + c) * R) >> 1) + (r0 >> 1) + wq] = lo | (hi << 16);
    }
}

// ---------- dual LayerNorm: fp32 x -> bf16 nx, f (one pass) ----------------
__global__ __launch_bounds__(256) void ln_dual(const float* __restrict__ x,
        const float* __restrict__ aw, const float* __restrict__ ab,
        const float* __restrict__ fw, const float* __restrict__ fb,
        u16* __restrict__ nx, u16* __restrict__ f) {
    int row = blockIdx.x;                // 0..B*S-1
    const float* xr = x + (size_t)row * D_;
    int base = threadIdx.x * 8;
    float4 xa = *(const float4*)&xr[base];
    float4 xb = *(const float4*)&xr[base + 4];
    float xv[8] = {xa.x, xa.y, xa.z, xa.w, xb.x, xb.y, xb.z, xb.w};
    float s = 0.f, s2 = 0.f;
#pragma unroll
    for (int i = 0; i < 8; ++i) { s += xv[i]; s2 += xv[i] * xv[i]; }
    s = wave_sum(s); s2 = wave_sum(s2);
    __shared__ float r1[4], r2[4];
    int w = threadIdx.x >> 6;
    if ((threadIdx.x & 63) == 0) { r1[w] = s; r2[w] = s2; }
    __syncthreads();
    float ts  = r1[0] + r1[1] + r1[2] + r1[3];
    float ts2 = r2[0] + r2[1] + r2[2] + r2[3];
    float mean = ts * (1.f / D_);
    float var  = ts2 * (1.f / D_) - mean * mean;
    float inv  = rsqrtf(var + EPS_);
    float4 wa0 = *(const float4*)&aw[base], wa1 = *(const float4*)&aw[base + 4];
    float4 ba0 = *(const float4*)&ab[base], ba1 = *(const float4*)&ab[base + 4];
    float4 wf0 = *(const float4*)&fw[base], wf1 = *(const float4*)&fw[base + 4];
    float4 bf0 = *(const float4*)&fb[base], bf1 = *(const float4*)&fb[base + 4];
    float wav[8] = {wa0.x, wa0.y, wa0.z, wa0.w, wa1.x, wa1.y, wa1.z, wa1.w};
    float bav[8] = {ba0.x, ba0.y, ba0.z, ba0.w, ba1.x, ba1.y, ba1.z, ba1.w};
    float wfv[8] = {wf0.x, wf0.y, wf0.z, wf0.w, wf1.x, wf1.y, wf1.z, wf1.w};
    float bfv[8] = {bf0.x, bf0.y, bf0.z, bf0.w, bf1.x, bf1.y, bf1.z, bf1.w};
    union { uint4 v; u16 s[8]; } o1, o2;
#pragma unroll
    for (int i = 0; i < 8; ++i) {
        float t = (xv[i] - mean) * inv;
        o1.s[i] = f2b(t * wav[i] + bav[i]);
        o2.s[i] = f2b(t * wfv[i] + bfv[i]);
    }
    *(uint4*)&nx[(size_t)row * D_ + base] = o1.v;
    *(uint4*)&f [(size_t)row * D_ + base] = o2.v;
}

// ---------------- MFMA GEMM: 128^2 tile, BK=64, swizzled LDS ---------------
// m97 2-phase structure with BK=64 + XOR LDS swizzle (QKV 99-102us @ ~48%
// MfmaUtil, conflicts 0).
// SWZ=0: plain 2D grid.  SWZ=1: WO/W2 map (grid 512, 8 XCD supertiles of
// 8x8 tiles).  SWZ=2: FFN1 map (grid 1024, 8 XCDs as 2x4 bands of 16x8).
// EPI 0: bf16 out.  EPI 1: fp32 out, += fp32 residual.  EPI 2: bf16, GELU.
template <int EPI, int SWZ>
__global__ __launch_bounds__(256, 2) void gemm_bt(
        const u16* __restrict__ A, const u16* __restrict__ BT,
        const float* __restrict__ bias, const float* __restrict__ res,
        void* __restrict__ Cv, int M, int N, int K) {
    __shared__ __align__(16) u16 As[128][64];
    __shared__ __align__(16) u16 Bs[128][64];
    int m0, n0;
    if (SWZ == 0) {
        m0 = blockIdx.y * 128; n0 = blockIdx.x * 128;
    } else if (SWZ == 1) {
        // grid = 512: XCD xc owns the 8x8-tile supertile (xc>>1, xc&1)
        int bid = blockIdx.x;
        int xc = bid & 7, ii = bid >> 3;
        int by = (xc >> 1) * 8 + (ii >> 3);
        int bx = (xc & 1) * 8 + (ii & 7);
        m0 = by * 128; n0 = bx * 128;
    } else {
        // grid = 1024 (32x32 tiles): XCD xc owns a 16x8-tile region
        int bid = blockIdx.x;
        int xc = bid & 7, ii = bid >> 3;          // ii 0..127
        int by = (xc >> 2) * 16 + (ii >> 3);      // 2 row-bands of 16
        int bx = (xc & 3) * 8 + (ii & 7);         // 4 col-bands of 8
        m0 = by * 128; n0 = bx * 128;
    }
    int w = threadIdx.x >> 6, lane = threadIdx.x & 63;
    int wm = (w >> 1) * 64, wn = (w & 1) * 64;
    int row16 = lane & 15, quad = lane >> 4;
    int lr  = lane >> 3;                  // staging row-within-8 (0..7)
    int lcs = ((lane & 7) ^ lr) << 3;     // pre-swizzled source col (u16)
    int xr  = (lane & 7) << 3;            // read-side col XOR (row16&7 == lane&7)
    f32x4 acc[4][4] = {};
    for (int k0 = 0; k0 < K; k0 += 64) {
        __syncthreads();
        // wave w stages rows [w*32, w*32+32) of both 128x64 tiles (8 DMAs)
#pragma unroll
        for (int j = 0; j < 4; ++j) {
            int rb = w * 32 + j * 8;
            gld_lds16(&A [(size_t)(m0 + rb + lr) * K + k0 + lcs], &As[rb][0]);
            gld_lds16(&BT[(size_t)(n0 + rb + lr) * K + k0 + lcs], &Bs[rb][0]);
        }
        __syncthreads();
        bf16x8 af[4][2], bfr[4][2];
#pragma unroll
        for (int i = 0; i < 4; ++i)
#pragma unroll
            for (int ks = 0; ks < 2; ++ks) {
                af[i][ks]  = *(const bf16x8*)&As[wm + i * 16 + row16][(ks * 32 + quad * 8) ^ xr];
                bfr[i][ks] = *(const bf16x8*)&Bs[wn + i * 16 + row16][(ks * 32 + quad * 8) ^ xr];
            }
#pragma unroll
        for (int mi = 0; mi < 4; ++mi)
#pragma unroll
            for (int ni = 0; ni < 4; ++ni)
#pragma unroll
                for (int ks = 0; ks < 2; ++ks)
                    acc[mi][ni] = __builtin_amdgcn_mfma_f32_16x16x32_bf16(
                            af[mi][ks], bfr[ni][ks], acc[mi][ni], 0, 0, 0);
    }
#pragma unroll
    for (int mi = 0; mi < 4; ++mi) {
#pragma unroll
        for (int ni = 0; ni < 4; ++ni) {
            int gcol = n0 + wn + ni * 16 + row16;
            float bv = bias[gcol];
#pragma unroll
            for (int i = 0; i < 4; ++i) {
                int grow = m0 + wm + mi * 16 + quad * 4 + i;
                float vv = acc[mi][ni][i] + bv;
                if (EPI == 1) {
                    vv += res[(size_t)grow * N + gcol];
                    ((float*)Cv)[(size_t)grow * N + gcol] = vv;
                } else {
                    if (EPI == 2)
                        vv = vv * 0.5f * (1.0f + erff(vv * 0.70710678118654752f));
                    ((u16*)Cv)[(size_t)grow * N + gcol] = f2b(vv);
                }
            }
        }
    }
}

// ---------------- QK RMSNorm + partial RoPE (q,k only), u32-vectorized -----
// One wave per (b,s,h). Lane l holds dims (2l, 2l+1) as one u32.
// RoPE: out[2j]=x0[j]c-x1[j]s, out[2j+1]=x1[j]c+x0[j]s, x0[j]=dim j,
// x1[j]=dim 16+j  -> lanes 0..15 produce their pair via 4 shuffles.
__global__ __launch_bounds__(256) void qk_rope(const u32* __restrict__ qkv32,
        const float* __restrict__ qn_w, const float* __restrict__ kn_w,
        const float* __restrict__ freqs,
        u32* __restrict__ q32, u32* __restrict__ k32) {
    int w = threadIdx.x >> 6, lane = threadIdx.x & 63;
    int unit = blockIdx.x * 4 + w;           // b*S*H + s*H + h
    int h = unit & (H_ - 1);
    int s = (unit >> 4) & (S_ - 1);
    int b = unit >> 15;
    size_t inbase  = (size_t)(b * S_ + s) * (3 * D_ / 2) + h * (HD_ / 2);
    size_t outbase = ((size_t)((b * H_ + h) * S_) + s) * (HD_ / 2);
    float fc = 0.f, fs = 0.f;
    if (lane < 16) {
        fc = freqs[(s * 16 + lane) * 2];
        fs = freqs[(s * 16 + lane) * 2 + 1];
    }
#pragma unroll
    for (int part = 0; part < 2; ++part) {   // 0: q, 1: k
        const float* nw = part ? kn_w : qn_w;
        u32 wv = qkv32[inbase + part * (D_ / 2) + lane];
        float a0 = b2f((u16)(wv & 0xffffu));
        float a1 = b2f((u16)(wv >> 16));
        float ss = wave_sum(a0 * a0 + a1 * a1);
        float inv = rsqrtf(ss * (1.f / HD_) + EPS_);
        float2 nwp = *(const float2*)&nw[2 * lane];
        float n0 = a0 * inv * nwp.x;
        float n1 = a1 * inv * nwp.y;
        // gather x0[j]=dim j (lane j>>1, parity j&1), x1[j]=dim 16+j
        float e0 = __shfl(n0, lane >> 1), e1 = __shfl(n1, lane >> 1);
        float o0 = __shfl(n0, 8 + (lane >> 1)), o1 = __shfl(n1, 8 + (lane >> 1));
        float x0 = (lane & 1) ? e1 : e0;
        float x1 = (lane & 1) ? o1 : o0;
        float rv0 = x0 * fc - x1 * fs;
        float rv1 = x1 * fc + x0 * fs;
        float w0 = (lane < 16) ? rv0 : n0;
        float w1 = (lane < 16) ? rv1 : n1;
        u32* dst = part ? k32 : q32;
        dst[outbase + lane] = (u32)f2b(w0) | ((u32)f2b(w1) << 16);
    }
}

// -------- V transpose: qkv V-part [b][s][h][d] -> vt [b][h][d][s] ----------
__global__ __launch_bounds__(256) void v_transpose(const u32* __restrict__ qkv32,
                                                   u32* __restrict__ vt32) {
    __shared__ u32 tile[64][17];
    int bh = blockIdx.z; int b = bh >> 4, h = bh & 15;
    int s0 = blockIdx.x * 64, d0 = blockIdx.y * 32;
    int tid = threadIdx.x;
    int rr = tid >> 4, cc = tid & 15;          // rr 0..15, cc 0..15 (u32 cols)
#pragma unroll
    for (int i = 0; i < 4; ++i) {
        int s = s0 + rr + i * 16;
        tile[rr + i * 16][cc] =
            qkv32[(size_t)(b * S_ + s) * (3 * D_ / 2) + (2 * D_ + h * HD_ + d0) / 2 + cc];
    }
    __syncthreads();
    int dr = tid & 31, sc = tid >> 5;          // dr 0..31, sc 0..7
#pragma unroll
    for (int i = 0; i < 4; ++i) {
        int s2 = sc + i * 8;                   // s-pair index 0..31
        u32 w0 = tile[2 * s2][dr >> 1];
        u32 w1 = tile[2 * s2 + 1][dr >> 1];
        u32 h0 = (dr & 1) ? (w0 >> 16) : (w0 & 0xffffu);
        u32 h1 = (dr & 1) ? (w1 >> 16) : (w1 & 0xffffu);
        vt32[((size_t)bh * HD_ + d0 + dr) * (S_ / 2) + (s0 >> 1) + s2] = h0 | (h1 << 16);
    }
}

// ---------------- MFMA sliding-window causal flash attention ---------------
// R19 structure (LDS double-buffered DMA staging) + R20 bh-grouped XCD
// swizzle: XCD xc owns heads [xc*4, xc*4+4) -> per-XCD resident K/V ~2MB
// (L2-fits; tile reuse across neighboring-g blocks becomes L2-hits).
__global__ __launch_bounds__(256) void attn_mfma(
        const u16* __restrict__ q, const u16* __restrict__ k,
        const u16* __restrict__ vt, u16* __restrict__ y) {
    __shared__ __align__(16) u16 Ks [2][64][128];   // 32KB, unpadded (DMA dest)
    __shared__ __align__(16) u16 Vts[2][128][64];   // 32KB, unpadded (DMA dest)
    __shared__ __align__(16) u16 Ps [4][16][72];    // 9KB (per-wave, intra-wave use)
    int bid = blockIdx.x;
    int xc = bid & 7, ii = bid >> 3;       // ii 0..127
    int bh = xc * 4 + (ii >> 5);           // 4 heads per XCD
    int g  = ii & 31;
    int qbase = g * 64;
    size_t kvbase = (size_t)bh * S_ * HD_;
    size_t vtbase = (size_t)bh * HD_ * S_;
    int w = threadIdx.x >> 6, lane = threadIdx.x & 63;
    int col16 = lane & 15, quad = lane >> 4;
    int xr = (lane & 7) << 3;              // read col XOR ((row&7)<<3, row=*16+col16)
    int q0w = qbase + w * 16;
    bf16x8 af[4];
#pragma unroll
    for (int kb = 0; kb < 4; ++kb)
        af[kb] = *(const bf16x8*)&q[kvbase + (size_t)(q0w + col16) * HD_ + kb * 32 + quad * 8];
    f32x4 oacc[8] = {};
    float mrow[4], lrow[4];
#pragma unroll
    for (int i = 0; i < 4; ++i) { mrow[i] = -1e38f; lrow[i] = 0.f; }
    int t0 = g >= 4 ? g - 4 : 0;

    // DMA staging: source col-slot pre-swizzled with (row&7) so the read
    // col ^ ((row&7)<<3) recovers linear data (gemm_bt pattern).
    auto stageK = [&](int buf, int t) {
#pragma unroll
        for (int j = 0; j < 4; ++j) {
            int rb  = w * 16 + j * 4;
            int row = rb + (lane >> 4);
            int ss  = (lane & 15) ^ (row & 7);
            gld_lds16(&k[kvbase + (size_t)(t * 64 + row) * HD_ + ss * 8],
                      &Ks[buf][rb][0]);
        }
    };
    auto stageV = [&](int buf, int t) {
#pragma unroll
        for (int j = 0; j < 4; ++j) {
            int rb  = w * 32 + j * 8;
            int row = rb + (lane >> 3);
            int ss  = (lane & 7) ^ (lane >> 3);
            gld_lds16(&vt[vtbase + (size_t)row * S_ + t * 64 + ss * 8],
                      &Vts[buf][rb][0]);
        }
    };

    stageK(0, t0); stageV(0, t0);   // prologue
    int cur = 0;
    for (int t = t0; t <= g; ++t) {
        __syncthreads();            // drains outstanding DMA: buf[cur] ready
        if (t < g) { stageK(cur ^ 1, t + 1); stageV(cur ^ 1, t + 1); }
        f32x4 sacc[4] = {};
#pragma unroll
        for (int ks = 0; ks < 4; ++ks)
#pragma unroll
            for (int kb = 0; kb < 4; ++kb) {
                bf16x8 bf = *(const bf16x8*)&Ks[cur][ks * 16 + col16][(kb * 32 + quad * 8) ^ xr];
                sacc[ks] = __builtin_amdgcn_mfma_f32_16x16x32_bf16(af[kb], bf, sacc[ks], 0, 0, 0);
            }
        float pm[4][4];
        float tmax[4] = {-3e38f, -3e38f, -3e38f, -3e38f};
#pragma unroll
        for (int ks = 0; ks < 4; ++ks) {
            int jg = t * 64 + ks * 16 + col16;
#pragma unroll
            for (int i = 0; i < 4; ++i) {
                int qi = q0w + quad * 4 + i;
                bool valid = (jg <= qi) && (qi - jg < WIN_);
                float sv = valid ? sacc[ks][i] * SCALE_ : -3e38f;
                pm[ks][i] = sv;
                tmax[i] = fmaxf(tmax[i], sv);
            }
        }
#pragma unroll
        for (int off = 8; off >= 1; off >>= 1)
#pragma unroll
            for (int i = 0; i < 4; ++i)
                tmax[i] = fmaxf(tmax[i], __shfl_xor(tmax[i], off));
        float alpha[4], psum[4];
#pragma unroll
        for (int i = 0; i < 4; ++i) {
            float mnew = fmaxf(mrow[i], tmax[i]);
            alpha[i] = __expf(mrow[i] - mnew);
            mrow[i] = mnew;
            psum[i] = 0.f;
        }
#pragma unroll
        for (int ks = 0; ks < 4; ++ks)
#pragma unroll
            for (int i = 0; i < 4; ++i) {
                float p = __expf(pm[ks][i] - mrow[i]);
                psum[i] += p;
                Ps[w][quad * 4 + i][ks * 16 + col16] = f2b(p);
            }
#pragma unroll
        for (int off = 8; off >= 1; off >>= 1)
#pragma unroll
            for (int i = 0; i < 4; ++i)
                psum[i] += __shfl_xor(psum[i], off);
#pragma unroll
        for (int i = 0; i < 4; ++i)
            lrow[i] = lrow[i] * alpha[i] + psum[i];
#pragma unroll
        for (int ns = 0; ns < 8; ++ns)
#pragma unroll
            for (int i = 0; i < 4; ++i)
                oacc[ns][i] *= alpha[i];
#pragma unroll
        for (int c = 0; c < 2; ++c) {
            bf16x8 pf = *(const bf16x8*)&Ps[w][col16][c * 32 + quad * 8];
#pragma unroll
            for (int ns = 0; ns < 8; ++ns) {
                bf16x8 vf = *(const bf16x8*)&Vts[cur][ns * 16 + col16][(c * 32 + quad * 8) ^ xr];
                oacc[ns] = __builtin_amdgcn_mfma_f32_16x16x32_bf16(pf, vf, oacc[ns], 0, 0, 0);
            }
        }
        __syncthreads();            // all reads of buf[cur] done; t+1 DMA drains (~free)
        cur ^= 1;
    }
    int b = bh >> 4, hh = bh & 15;
#pragma unroll
    for (int i = 0; i < 4; ++i) {
        int qi = q0w + quad * 4 + i;
        float invl = 1.f / lrow[i];
        size_t ob = (size_t)(b * S_ + qi) * D_ + hh * HD_;
#pragma unroll
        for (int ns = 0; ns < 8; ++ns)
            y[ob + ns * 16 + col16] = f2b(oacc[ns][i] * invl);
    }
}

// ---------------------------- host orchestration ---------------------------
extern "C" void kernel_launch(void* const* d_in, const int* in_sizes, int n_in,
                              void* d_out, int out_size, void* d_ws, size_t ws_size,
                              hipStream_t stream) {
    const float* x      = (const float*)d_in[0];
    const float* freqs  = (const float*)d_in[1];
    // d_in[2] = mask (unused; computed analytically)
    const float* wqkv_w = (const float*)d_in[3];
    const float* wqkv_b = (const float*)d_in[4];
    const float* wo_w   = (const float*)d_in[5];
    const float* wo_b   = (const float*)d_in[6];
    const float* qn_w   = (const float*)d_in[7];
    const float* kn_w   = (const float*)d_in[8];
    const float* aln_w  = (const float*)d_in[9];
    const float* aln_b  = (const float*)d_in[10];
    const float* fln_w  = (const float*)d_in[11];
    const float* fln_b  = (const float*)d_in[12];
    const float* w1_w   = (const float*)d_in[13];
    const float* w1_b   = (const float*)d_in[14];
    const float* w2_w   = (const float*)d_in[15];
    const float* w2_b   = (const float*)d_in[16];
    float* out = (float*)d_out;

    char* ws = (char*)d_ws;
    size_t off = 0;
    auto alloc = [&](size_t bytes) { char* p = ws + off; off += (bytes + 255) & ~(size_t)255; return (u16*)p; };
    const size_t E = sizeof(u16);
    u16* wt_qkv = alloc((size_t)D_ * 3 * D_ * E);       // bf16 [6144,2048]
    u16* wt_wo  = alloc((size_t)D_ * D_ * E);           // bf16 [2048,2048]
    u16* wt_w1  = alloc((size_t)D_ * FF_ * E);          // bf16 [4096,2048]
    u16* wt_w2  = alloc((size_t)FF_ * D_ * E);          // bf16 [2048,4096]
    u16* nx     = alloc((size_t)B_ * S_ * D_ * E);      // bf16; reused as y
    u16* f      = alloc((size_t)B_ * S_ * D_ * E);      // bf16
    u16* qkv    = alloc((size_t)B_ * S_ * 3 * D_ * E);  // bf16; reused as tmid
    u16* qb     = alloc((size_t)B_ * S_ * D_ * E);      // bf16 [b][h][s][d]
    u16* kb     = alloc((size_t)B_ * S_ * D_ * E);      // bf16 [b][h][s][d]
    u16* vtb    = alloc((size_t)B_ * S_ * D_ * E);      // bf16 [b][h][d][s]
    u16* y    = nx;    // nx consumed by QKV GEMM before attention writes y
    u16* tmid = qkv;   // qkv consumed by qk_rope/v_transpose before FFN1
    float* h  = out;   // h lives in d_out

    if (off > ws_size) return;  // tripwire -> finite err signature

    const int M = B_ * S_;  // 4096

    // all 4 weight transposes in one launch (8192 blocks)
    transpose_k4<<<8192, 256, 0, stream>>>(wqkv_w, wt_qkv, wo_w, wt_wo,
                                           w1_w, wt_w1, w2_w, wt_w2);

    ln_dual<<<M, 256, 0, stream>>>(x, aln_w, aln_b, fln_w, fln_b, nx, f);

    // QKV: proven R13 2D-grid path
    gemm_bt<0, 0><<<dim3(3 * D_ / 128, M / 128), 256, 0, stream>>>(
            nx, wt_qkv, wqkv_b, nullptr, qkv, M, 3 * D_, D_);

    qk_rope<<<B_ * S_ * H_ / 4, 256, 0, stream>>>((const u32*)qkv, qn_w, kn_w, freqs, (u32*)qb, (u32*)kb);
    v_transpose<<<dim3(S_ / 64, HD_ / 32, B_ * H_), 256, 0, stream>>>((const u32*)qkv, (u32*)vtb);

    attn_mfma<<<B_ * H_ * (S_ / 64), 256, 0, stream>>>(qb, kb, vtb, y);

    // FFN1: 16x8 XCD-supertile remap (grid 1024)
    gemm_bt<2, 2><<<(FF_ / 128) * (M / 128), 256, 0, stream>>>(
            f, wt_w1, w1_b, nullptr, tmid, M, FF_, D_);

    // WO/W2: 8x8 XCD-supertile remap (grid 512)
    gemm_bt<1, 1><<<(D_ / 128) * (M / 128), 256, 0, stream>>>(
            y, wt_wo, wo_b, x, h, M, D_, D_);

    gemm_bt<1, 1><<<(D_ / 128) * (M / 128), 256, 0, stream>>>(
            tmid, wt_w2, w2_b, h, out, M, D_, FF_);
}